// Round 1
// baseline (413.260 us; speedup 1.0000x reference)
//
#include <hip/hip_runtime.h>

typedef unsigned short ushort_t;
typedef __attribute__((ext_vector_type(8))) __bf16 bf16x8;
typedef __attribute__((ext_vector_type(4))) float f32x4;
typedef __attribute__((ext_vector_type(4))) unsigned short us4;
typedef __attribute__((ext_vector_type(8))) unsigned short us8;

#define AS1 __attribute__((address_space(1)))
#define AS3 __attribute__((address_space(3)))

__device__ __forceinline__ unsigned short f2bf(float f) {
    unsigned u = __float_as_uint(f);
    u += 0x7fff + ((u >> 16) & 1);   // RNE
    return (unsigned short)(u >> 16);
}

// ---------------------------------------------------------------- convert x
__global__ void k_convert_x(const float* __restrict__ x, ushort_t* __restrict__ xb, int n4) {
    int i = blockIdx.x * blockDim.x + threadIdx.x;
    int stride = gridDim.x * blockDim.x;
    for (; i < n4; i += stride) {
        float4 f = reinterpret_cast<const float4*>(x)[i];
        us4 o = { f2bf(f.x), f2bf(f.y), f2bf(f.z), f2bf(f.w) };
        reinterpret_cast<us4*>(xb)[i] = o;
    }
}

// ------------------------------------------------- transpose weights -> bf16 [n][k]
__global__ void k_transpose_w(const float* __restrict__ wq, const float* __restrict__ wk,
                              const float* __restrict__ wv, const float* __restrict__ wo,
                              ushort_t* __restrict__ wqkvt, ushort_t* __restrict__ wot) {
    __shared__ float t[64][65];
    int bx = blockIdx.x;
    int w = bx >> 8;            // 0..3 : WQ WK WV WO
    int ti = bx & 255;
    int k0 = (ti >> 4) * 64, n0 = (ti & 15) * 64;
    const float* src = (w == 0) ? wq : (w == 1) ? wk : (w == 2) ? wv : wo;
    ushort_t* dst = (w < 3) ? (wqkvt + (size_t)w * 1048576) : wot;
    for (int i = threadIdx.x; i < 4096; i += 256) {
        int r = i >> 6, c = i & 63;
        t[c][r] = src[(size_t)(k0 + r) * 1024 + n0 + c];
    }
    __syncthreads();
    for (int i = threadIdx.x; i < 4096; i += 256) {
        int r = i >> 6, c = i & 63;
        dst[(size_t)(n0 + r) * 1024 + k0 + c] = f2bf(t[r][c]);
    }
}

// ---------------------------------------------------------------- QKV GEMM
// C[8192,3072] = xb[8192,1024] * W^T(rows=n,cols=k); scatter into [B,H,T,Dh]
__global__ __launch_bounds__(256) void k_gemm_qkv(
    const ushort_t* __restrict__ xb, const ushort_t* __restrict__ wt,
    ushort_t* __restrict__ qd, ushort_t* __restrict__ kd, ushort_t* __restrict__ vd) {
    __shared__ ushort_t lA[128 * 32];
    __shared__ ushort_t lB[128 * 32];
    const int tid = threadIdx.x, wid = tid >> 6, lane = tid & 63;
    const int lr = lane & 15, lg = lane >> 4;
    const int wm = wid >> 1, wn = wid & 1;
    const int bx = blockIdx.x;   // 24 col tiles
    const int by = blockIdx.y;   // 64 row tiles
    const int row0 = by * 128, col0 = bx * 128;
    const int crow = lane >> 2;        // staging row within 16-row chunk
    const int coff = (lane & 3) * 8;   // staging ushort offset within 32-us row

    f32x4 acc[4][4] = {};

    for (int k0 = 0; k0 < 1024; k0 += 32) {
        for (int c = wid; c < 8; c += 4) {
            const ushort_t* ga = xb + (size_t)(row0 + c * 16 + crow) * 1024 + k0 + coff;
            __builtin_amdgcn_global_load_lds((const AS1 void*)ga, (AS3 void*)(lA + c * 512), 16, 0, 0);
            const ushort_t* gb = wt + (size_t)(col0 + c * 16 + crow) * 1024 + k0 + coff;
            __builtin_amdgcn_global_load_lds((const AS1 void*)gb, (AS3 void*)(lB + c * 512), 16, 0, 0);
        }
        __syncthreads();
        bf16x8 af[4], bfr[4];
#pragma unroll
        for (int i = 0; i < 4; ++i) {
            af[i]  = *reinterpret_cast<const bf16x8*>(lA + (wm * 64 + i * 16 + lr) * 32 + lg * 8);
            bfr[i] = *reinterpret_cast<const bf16x8*>(lB + (wn * 64 + i * 16 + lr) * 32 + lg * 8);
        }
#pragma unroll
        for (int mi = 0; mi < 4; ++mi)
#pragma unroll
            for (int ni = 0; ni < 4; ++ni)
                acc[mi][ni] = __builtin_amdgcn_mfma_f32_16x16x32_bf16(af[mi], bfr[ni], acc[mi][ni], 0, 0, 0);
        __syncthreads();
    }

    const int w = bx >> 3;  // 0:Q 1:K 2:V (uniform per block)
    ushort_t* dst = (w == 0) ? qd : (w == 1) ? kd : vd;
#pragma unroll
    for (int mi = 0; mi < 4; ++mi) {
#pragma unroll
        for (int ni = 0; ni < 4; ++ni) {
            int col = col0 + wn * 64 + ni * 16 + lr;
            int c1 = col & 1023;
            int h = c1 >> 6, dh = c1 & 63;
#pragma unroll
            for (int e = 0; e < 4; ++e) {
                int row = row0 + wm * 64 + mi * 16 + lg * 4 + e;
                int b = row >> 11, t = row & 2047;
                dst[(((size_t)(b * 16 + h)) * 2048 + t) * 64 + dh] = f2bf(acc[mi][ni][e]);
            }
        }
    }
}

// ---------------------------------------------------------------- attention
__global__ __launch_bounds__(256) void k_attn(
    const ushort_t* __restrict__ q, const ushort_t* __restrict__ k,
    const ushort_t* __restrict__ v, ushort_t* __restrict__ ctx) {
    __shared__ ushort_t lK[64 * 64];       // [key][dh] rows 128B, XOR-swizzled 16B slots
    __shared__ ushort_t lV[64 * 72];       // [dh][key] transposed, +8 pad
    __shared__ ushort_t lP[4][16 * 72];    // per-wave P [qrow][key], +8 pad

    const int tid = threadIdx.x, wid = tid >> 6, lane = tid & 63;
    const int lr = lane & 15, lg = lane >> 4;
    const int bid = blockIdx.x;
    const int bh = bid >> 5, qt = bid & 31;
    const int q0 = qt * 64;
    const size_t base = (size_t)bh * 2048 * 64;
    const ushort_t* qb = q + base;
    const ushort_t* kb = k + base;
    const ushort_t* vb = v + base;

    const int qrow = q0 + wid * 16 + lr;
    bf16x8 aq[2];
    aq[0] = *reinterpret_cast<const bf16x8*>(qb + (size_t)qrow * 64 + lg * 8);
    aq[1] = *reinterpret_cast<const bf16x8*>(qb + (size_t)qrow * 64 + 32 + lg * 8);

    f32x4 acc[4] = {};
    float mrow[4] = {-1e30f, -1e30f, -1e30f, -1e30f};
    float lsum[4] = {};

    for (int j0 = 0; j0 <= q0; j0 += 64) {
        // ---- stage K (swizzled) and V^T (padded) : 64x64 bf16 each
#pragma unroll
        for (int it = 0; it < 2; ++it) {
            int idx = tid + it * 256;
            int krow = idx >> 3;
            int koff = (idx & 7) * 8;
            bf16x8 kvv = *reinterpret_cast<const bf16x8*>(kb + (size_t)(j0 + krow) * 64 + koff);
            int sw = (koff * 2) ^ ((krow & 7) << 4);
            *reinterpret_cast<bf16x8*>(reinterpret_cast<char*>(lK) + krow * 128 + sw) = kvv;
            us8 vv = *reinterpret_cast<const us8*>(vb + (size_t)(j0 + krow) * 64 + koff);
#pragma unroll
            for (int e = 0; e < 8; ++e)
                lV[(koff + e) * 72 + krow] = vv[e];
        }
        __syncthreads();

        // ---- S = Q K^T
        f32x4 sf[4] = {};
#pragma unroll
        for (int ks = 0; ks < 2; ++ks) {
#pragma unroll
            for (int ni = 0; ni < 4; ++ni) {
                int key = ni * 16 + lr;
                int boff = (ks * 64 + lg * 16) ^ ((key & 7) << 4);
                bf16x8 bk = *reinterpret_cast<const bf16x8*>(
                    reinterpret_cast<const char*>(lK) + key * 128 + boff);
                sf[ni] = __builtin_amdgcn_mfma_f32_16x16x32_bf16(aq[ks], bk, sf[ni], 0, 0, 0);
            }
        }

        // ---- scale + causal mask
        float s[4][4];
        const bool diag = (j0 == q0);
#pragma unroll
        for (int ni = 0; ni < 4; ++ni) {
            int key_g = j0 + ni * 16 + lr;
#pragma unroll
            for (int e = 0; e < 4; ++e) {
                float val = sf[ni][e] * 0.125f;
                if (diag) {
                    int row_g = q0 + wid * 16 + lg * 4 + e;
                    if (key_g > row_g) val = -1e30f;
                }
                s[ni][e] = val;
            }
        }

        // ---- online softmax (rows live across the 16 lanes sharing lg)
        float scl[4];
#pragma unroll
        for (int e = 0; e < 4; ++e) {
            float x0 = fmaxf(fmaxf(s[0][e], s[1][e]), fmaxf(s[2][e], s[3][e]));
            x0 = fmaxf(x0, __shfl_xor(x0, 1));
            x0 = fmaxf(x0, __shfl_xor(x0, 2));
            x0 = fmaxf(x0, __shfl_xor(x0, 4));
            x0 = fmaxf(x0, __shfl_xor(x0, 8));
            float mn = fmaxf(mrow[e], x0);
            scl[e] = __expf(mrow[e] - mn);
            mrow[e] = mn;
        }
        float rs[4] = {};
#pragma unroll
        for (int ni = 0; ni < 4; ++ni) {
#pragma unroll
            for (int e = 0; e < 4; ++e) {
                float p = __expf(s[ni][e] - mrow[e]);
                rs[e] += p;
                lP[wid][(lg * 4 + e) * 72 + ni * 16 + lr] = f2bf(p);
            }
        }
#pragma unroll
        for (int e = 0; e < 4; ++e) {
            float r = rs[e];
            r += __shfl_xor(r, 1);
            r += __shfl_xor(r, 2);
            r += __shfl_xor(r, 4);
            r += __shfl_xor(r, 8);
            lsum[e] = lsum[e] * scl[e] + r;
        }
#pragma unroll
        for (int ni = 0; ni < 4; ++ni)
#pragma unroll
            for (int e = 0; e < 4; ++e)
                acc[ni][e] *= scl[e];

        // ---- PV
#pragma unroll
        for (int ks = 0; ks < 2; ++ks) {
            bf16x8 ap = *reinterpret_cast<const bf16x8*>(&lP[wid][lr * 72 + ks * 32 + lg * 8]);
#pragma unroll
            for (int ni = 0; ni < 4; ++ni) {
                bf16x8 bv = *reinterpret_cast<const bf16x8*>(&lV[(ni * 16 + lr) * 72 + ks * 32 + lg * 8]);
                acc[ni] = __builtin_amdgcn_mfma_f32_16x16x32_bf16(ap, bv, acc[ni], 0, 0, 0);
            }
        }
        __syncthreads();
    }

    // ---- epilogue: ctx[b*T+t][h*64+dh] bf16
    const int b = bh >> 4, h = bh & 15;
#pragma unroll
    for (int ni = 0; ni < 4; ++ni) {
#pragma unroll
        for (int e = 0; e < 4; ++e) {
            int t = q0 + wid * 16 + lg * 4 + e;
            ctx[(size_t)(b * 2048 + t) * 1024 + h * 64 + ni * 16 + lr] =
                f2bf(acc[ni][e] / lsum[e]);
        }
    }
}

// ---------------------------------------------------------------- out GEMM (+bias, f32 out)
__global__ __launch_bounds__(256) void k_gemm_out(
    const ushort_t* __restrict__ cb, const ushort_t* __restrict__ wot,
    const float* __restrict__ bO, float* __restrict__ out) {
    __shared__ ushort_t lA[128 * 32];
    __shared__ ushort_t lB[128 * 32];
    const int tid = threadIdx.x, wid = tid >> 6, lane = tid & 63;
    const int lr = lane & 15, lg = lane >> 4;
    const int wm = wid >> 1, wn = wid & 1;
    const int bx = blockIdx.x;   // 8 col tiles
    const int by = blockIdx.y;   // 64 row tiles
    const int row0 = by * 128, col0 = bx * 128;
    const int crow = lane >> 2;
    const int coff = (lane & 3) * 8;

    f32x4 acc[4][4] = {};

    for (int k0 = 0; k0 < 1024; k0 += 32) {
        for (int c = wid; c < 8; c += 4) {
            const ushort_t* ga = cb + (size_t)(row0 + c * 16 + crow) * 1024 + k0 + coff;
            __builtin_amdgcn_global_load_lds((const AS1 void*)ga, (AS3 void*)(lA + c * 512), 16, 0, 0);
            const ushort_t* gb = wot + (size_t)(col0 + c * 16 + crow) * 1024 + k0 + coff;
            __builtin_amdgcn_global_load_lds((const AS1 void*)gb, (AS3 void*)(lB + c * 512), 16, 0, 0);
        }
        __syncthreads();
        bf16x8 af[4], bfr[4];
#pragma unroll
        for (int i = 0; i < 4; ++i) {
            af[i]  = *reinterpret_cast<const bf16x8*>(lA + (wm * 64 + i * 16 + lr) * 32 + lg * 8);
            bfr[i] = *reinterpret_cast<const bf16x8*>(lB + (wn * 64 + i * 16 + lr) * 32 + lg * 8);
        }
#pragma unroll
        for (int mi = 0; mi < 4; ++mi)
#pragma unroll
            for (int ni = 0; ni < 4; ++ni)
                acc[mi][ni] = __builtin_amdgcn_mfma_f32_16x16x32_bf16(af[mi], bfr[ni], acc[mi][ni], 0, 0, 0);
        __syncthreads();
    }

#pragma unroll
    for (int mi = 0; mi < 4; ++mi) {
#pragma unroll
        for (int ni = 0; ni < 4; ++ni) {
            int col = col0 + wn * 64 + ni * 16 + lr;
            float bias = bO[col];
#pragma unroll
            for (int e = 0; e < 4; ++e) {
                int row = row0 + wm * 64 + mi * 16 + lg * 4 + e;
                out[(size_t)row * 1024 + col] = acc[mi][ni][e] + bias;
            }
        }
    }
}

// ---------------------------------------------------------------- launch
extern "C" void kernel_launch(void* const* d_in, const int* in_sizes, int n_in,
                              void* d_out, int out_size, void* d_ws, size_t ws_size,
                              hipStream_t stream) {
    const float* x  = (const float*)d_in[0];
    const float* wq = (const float*)d_in[1];
    const float* wk = (const float*)d_in[2];
    const float* wv = (const float*)d_in[3];
    const float* wo = (const float*)d_in[4];
    const float* bo = (const float*)d_in[5];
    float* out = (float*)d_out;

    char* ws = (char*)d_ws;
    ushort_t* xb    = (ushort_t*)(ws);                 // 16 MB   x bf16 [8192][1024]
    ushort_t* wqkvt = (ushort_t*)(ws + 16777216);      // 6 MB    [3][1024 n][1024 k]
    ushort_t* wot   = (ushort_t*)(ws + 23068672);      // 2 MB    [1024 n][1024 k]
    ushort_t* qd    = (ushort_t*)(ws + 25165824);      // 16 MB   [B,H,T,Dh]
    ushort_t* kd    = (ushort_t*)(ws + 41943040);      // 16 MB
    ushort_t* vd    = (ushort_t*)(ws + 58720256);      // 16 MB
    ushort_t* cd    = (ushort_t*)(ws + 75497472);      // 16 MB   ctx bf16 [8192][1024]

    k_convert_x<<<2048, 256, 0, stream>>>(x, xb, 8192 * 1024 / 4);
    k_transpose_w<<<1024, 256, 0, stream>>>(wq, wk, wv, wo, wqkvt, wot);
    k_gemm_qkv<<<dim3(24, 64), 256, 0, stream>>>(xb, wqkvt, qd, kd, vd);
    k_attn<<<2048, 256, 0, stream>>>(qd, kd, vd, cd);
    k_gemm_out<<<dim3(8, 64), 256, 0, stream>>>(cd, wot, bo, out);
}

// Round 2
// 221.482 us; speedup vs baseline: 1.8659x; 1.8659x over previous
//
#include <hip/hip_runtime.h>

typedef unsigned short ushort_t;
typedef __attribute__((ext_vector_type(8))) __bf16 bf16x8;
typedef __attribute__((ext_vector_type(4))) float f32x4;
typedef __attribute__((ext_vector_type(16))) float f32x16;
typedef __attribute__((ext_vector_type(4))) unsigned short us4;
typedef __attribute__((ext_vector_type(8))) unsigned short us8;
typedef __attribute__((ext_vector_type(4))) unsigned int u32x4;

#define AS1 __attribute__((address_space(1)))
#define AS3 __attribute__((address_space(3)))

__device__ __forceinline__ unsigned short f2bf(float f) {
    unsigned u = __float_as_uint(f);
    u += 0x7fff + ((u >> 16) & 1);   // RNE
    return (unsigned short)(u >> 16);
}

__device__ __forceinline__ unsigned cvtpk_bf16(float lo, float hi) {
    unsigned r;
    asm("v_cvt_pk_bf16_f32 %0, %1, %2" : "=v"(r) : "v"(lo), "v"(hi));
    return r;
}

// ---------------------------------------------------------------- convert x
__global__ void k_convert_x(const float* __restrict__ x, ushort_t* __restrict__ xb, int n4) {
    int i = blockIdx.x * blockDim.x + threadIdx.x;
    int stride = gridDim.x * blockDim.x;
    for (; i < n4; i += stride) {
        float4 f = reinterpret_cast<const float4*>(x)[i];
        us4 o = { f2bf(f.x), f2bf(f.y), f2bf(f.z), f2bf(f.w) };
        reinterpret_cast<us4*>(xb)[i] = o;
    }
}

// ------------------------------------------------- transpose weights -> bf16 [n][k]
__global__ void k_transpose_w(const float* __restrict__ wq, const float* __restrict__ wk,
                              const float* __restrict__ wv, const float* __restrict__ wo,
                              ushort_t* __restrict__ wqkvt, ushort_t* __restrict__ wot) {
    __shared__ float t[64][65];
    int bx = blockIdx.x;
    int w = bx >> 8;            // 0..3 : WQ WK WV WO
    int ti = bx & 255;
    int k0 = (ti >> 4) * 64, n0 = (ti & 15) * 64;
    const float* src = (w == 0) ? wq : (w == 1) ? wk : (w == 2) ? wv : wo;
    ushort_t* dst = (w < 3) ? (wqkvt + (size_t)w * 1048576) : wot;
    for (int i = threadIdx.x; i < 4096; i += 256) {
        int r = i >> 6, c = i & 63;
        t[c][r] = src[(size_t)(k0 + r) * 1024 + n0 + c];
    }
    __syncthreads();
    for (int i = threadIdx.x; i < 4096; i += 256) {
        int r = i >> 6, c = i & 63;
        dst[(size_t)(n0 + r) * 1024 + k0 + c] = f2bf(t[r][c]);
    }
}

// ---------------------------------------------------------------- QKV GEMM
__global__ __launch_bounds__(256) void k_gemm_qkv(
    const ushort_t* __restrict__ xb, const ushort_t* __restrict__ wt,
    ushort_t* __restrict__ qd, ushort_t* __restrict__ kd, ushort_t* __restrict__ vd) {
    __shared__ ushort_t lA[128 * 32];
    __shared__ ushort_t lB[128 * 32];
    const int tid = threadIdx.x, wid = tid >> 6, lane = tid & 63;
    const int lr = lane & 15, lg = lane >> 4;
    const int wm = wid >> 1, wn = wid & 1;
    const int bx = blockIdx.x;   // 24 col tiles
    const int by = blockIdx.y;   // 64 row tiles
    const int row0 = by * 128, col0 = bx * 128;
    const int crow = lane >> 2;
    const int coff = (lane & 3) * 8;

    f32x4 acc[4][4] = {};

    for (int k0 = 0; k0 < 1024; k0 += 32) {
        for (int c = wid; c < 8; c += 4) {
            const ushort_t* ga = xb + (size_t)(row0 + c * 16 + crow) * 1024 + k0 + coff;
            __builtin_amdgcn_global_load_lds((const AS1 void*)ga, (AS3 void*)(lA + c * 512), 16, 0, 0);
            const ushort_t* gb = wt + (size_t)(col0 + c * 16 + crow) * 1024 + k0 + coff;
            __builtin_amdgcn_global_load_lds((const AS1 void*)gb, (AS3 void*)(lB + c * 512), 16, 0, 0);
        }
        __syncthreads();
        bf16x8 af[4], bfr[4];
#pragma unroll
        for (int i = 0; i < 4; ++i) {
            af[i]  = *reinterpret_cast<const bf16x8*>(lA + (wm * 64 + i * 16 + lr) * 32 + lg * 8);
            bfr[i] = *reinterpret_cast<const bf16x8*>(lB + (wn * 64 + i * 16 + lr) * 32 + lg * 8);
        }
#pragma unroll
        for (int mi = 0; mi < 4; ++mi)
#pragma unroll
            for (int ni = 0; ni < 4; ++ni)
                acc[mi][ni] = __builtin_amdgcn_mfma_f32_16x16x32_bf16(af[mi], bfr[ni], acc[mi][ni], 0, 0, 0);
        __syncthreads();
    }

    const int w = bx >> 3;  // 0:Q 1:K 2:V (uniform per block)
    ushort_t* dst = (w == 0) ? qd : (w == 1) ? kd : vd;
#pragma unroll
    for (int mi = 0; mi < 4; ++mi) {
#pragma unroll
        for (int ni = 0; ni < 4; ++ni) {
            int col = col0 + wn * 64 + ni * 16 + lr;
            int c1 = col & 1023;
            int h = c1 >> 6, dh = c1 & 63;
#pragma unroll
            for (int e = 0; e < 4; ++e) {
                int row = row0 + wm * 64 + mi * 16 + lg * 4 + e;
                int b = row >> 11, t = row & 2047;
                dst[(((size_t)(b * 16 + h)) * 2048 + t) * 64 + dh] = f2bf(acc[mi][ni][e]);
            }
        }
    }
}

// ---------------------------------------------------------------- attention
// 4 waves x 32 q-rows = 128-row q-tile; two paired q-tiles per block (work = 34 KV-iters, uniform).
// Swapped QK^T (S^T = K x Q) -> lane owns P row for q = lane&31; ctx^T = V^T x P^T keeps
// softmax state and rescale lane-local. Only cross-lane op: shfl_xor(32).
__global__ __launch_bounds__(256) void k_attn(
    const ushort_t* __restrict__ q, const ushort_t* __restrict__ k,
    const ushort_t* __restrict__ v, ushort_t* __restrict__ ctx) {
    __shared__ ushort_t lK[64 * 72];        // [key][dh] rows padded to 144B (4-bank rotate)
    __shared__ unsigned int lVt[64 * 33];   // [dh][keypair] u32 = (V[2kp][dh], V[2kp+1][dh])

    const int tid = threadIdx.x, wid = tid >> 6, lane = tid & 63;
    const int l31 = lane & 31, hi = lane >> 5;
    const int bid = blockIdx.x;
    const int bh = bid >> 3, pi = bid & 7;
    const size_t base = (size_t)bh * 2048 * 64;
    const ushort_t* qg = q + base;
    const ushort_t* kg = k + base;
    const ushort_t* vg = v + base;
    const int b = bh >> 4, h = bh & 15;
    const float SC = 0.18033688f;  // 0.125 * log2(e)

#pragma unroll 1
    for (int pass = 0; pass < 2; ++pass) {
        const int qt = pass == 0 ? (15 - pi) : pi;
        const int q0 = qt * 128;
        const int q0w = q0 + wid * 32;
        const int qrow = q0w + l31;

        bf16x8 qf[4];
#pragma unroll
        for (int s = 0; s < 4; ++s)
            qf[s] = *reinterpret_cast<const bf16x8*>(qg + (size_t)qrow * 64 + s * 16 + hi * 8);

        f32x16 acc0 = {}, acc1 = {};
        float m = -1e30f, lsum = 0.f;

        const int jend = q0 + 128;
        for (int j0 = 0; j0 < jend; j0 += 64) {
            // ---- stage K [64][72]
#pragma unroll
            for (int it = 0; it < 2; ++it) {
                int idx = it * 256 + tid;
                int key = idx >> 3, d8 = (idx & 7) * 8;
                us8 kv = *reinterpret_cast<const us8*>(kg + (size_t)(j0 + key) * 64 + d8);
                *reinterpret_cast<us8*>(&lK[key * 72 + d8]) = kv;
            }
            // ---- stage V pair-transposed into [dh][kp] u32
            {
                int kp = tid >> 3, d8 = (tid & 7) * 8;
                u32x4 aw = *reinterpret_cast<const u32x4*>(vg + (size_t)(j0 + 2 * kp) * 64 + d8);
                u32x4 bw = *reinterpret_cast<const u32x4*>(vg + (size_t)(j0 + 2 * kp + 1) * 64 + d8);
#pragma unroll
                for (int jj = 0; jj < 4; ++jj) {
                    unsigned lo = __builtin_amdgcn_perm(bw[jj], aw[jj], 0x05040100u);
                    unsigned hv = __builtin_amdgcn_perm(bw[jj], aw[jj], 0x07060302u);
                    lVt[(d8 + 2 * jj) * 33 + kp] = lo;
                    lVt[(d8 + 2 * jj + 1) * 33 + kp] = hv;
                }
            }
            __syncthreads();

            if (j0 <= q0w + 31) {
                // ---- S^T = K x Q  (rows=keys, cols=q)
                f32x16 s0 = {}, s1 = {};
#pragma unroll
                for (int s = 0; s < 4; ++s) {
                    bf16x8 ka = *reinterpret_cast<const bf16x8*>(&lK[l31 * 72 + s * 16 + hi * 8]);
                    s0 = __builtin_amdgcn_mfma_f32_32x32x16_bf16(ka, qf[s], s0, 0, 0, 0);
                }
#pragma unroll
                for (int s = 0; s < 4; ++s) {
                    bf16x8 ka = *reinterpret_cast<const bf16x8*>(&lK[(32 + l31) * 72 + s * 16 + hi * 8]);
                    s1 = __builtin_amdgcn_mfma_f32_32x32x16_bf16(ka, qf[s], s1, 0, 0, 0);
                }

                // ---- scale + causal mask (key = j0 + kb*32 + (r&3)+8*(r>>2)+4*hi)
                float p0[16], p1[16];
                const bool needmask = (j0 + 63 > q0w);
#pragma unroll
                for (int r = 0; r < 16; ++r) {
                    float a = s0[r] * SC, c = s1[r] * SC;
                    if (needmask) {
                        int kl = j0 + (r & 3) + 8 * (r >> 2) + 4 * hi;
                        if (kl > qrow) a = -1e30f;
                        if (kl + 32 > qrow) c = -1e30f;
                    }
                    p0[r] = a; p1[r] = c;
                }

                // ---- online softmax (lane pair l, l^32 holds the 64 keys of row q=l31)
                float mx = p0[0];
#pragma unroll
                for (int r = 1; r < 16; ++r) mx = fmaxf(mx, p0[r]);
#pragma unroll
                for (int r = 0; r < 16; ++r) mx = fmaxf(mx, p1[r]);
                mx = fmaxf(mx, __shfl_xor(mx, 32));
                float mnew = fmaxf(m, mx);
                float scl = exp2f(m - mnew);
                m = mnew;
                float rs = 0.f;
#pragma unroll
                for (int r = 0; r < 16; ++r) {
                    float e0 = exp2f(p0[r] - m); p0[r] = e0; rs += e0;
                    float e1 = exp2f(p1[r] - m); p1[r] = e1; rs += e1;
                }
                rs += __shfl_xor(rs, 32);
                lsum = lsum * scl + rs;
#pragma unroll
                for (int r = 0; r < 16; ++r) { acc0[r] *= scl; acc1[r] *= scl; }

                // ---- P pack + half-exchange + PV (ctx^T += V^T x P^T)
#pragma unroll
                for (int kb = 0; kb < 2; ++kb) {
                    const float* pp = kb ? p1 : p0;
                    unsigned pw[8];
#pragma unroll
                    for (int g = 0; g < 4; ++g) {
                        pw[2 * g]     = cvtpk_bf16(pp[4 * g],     pp[4 * g + 1]);
                        pw[2 * g + 1] = cvtpk_bf16(pp[4 * g + 2], pp[4 * g + 3]);
                    }
                    unsigned X[2][2];
#pragma unroll
                    for (int j = 0; j < 2; ++j) {
#pragma unroll
                        for (int w = 0; w < 2; ++w) {
                            unsigned snd = hi ? pw[4 * j + w] : pw[4 * j + 2 + w];
                            X[j][w] = (unsigned)__shfl_xor((int)snd, 32);
                        }
                    }
#pragma unroll
                    for (int j = 0; j < 2; ++j) {
                        u32x4 fw;
                        fw[0] = hi ? X[j][0] : pw[4 * j + 0];
                        fw[1] = hi ? X[j][1] : pw[4 * j + 1];
                        fw[2] = hi ? pw[4 * j + 2] : X[j][0];
                        fw[3] = hi ? pw[4 * j + 3] : X[j][1];
                        bf16x8 pf = __builtin_bit_cast(bf16x8, fw);
                        int kp = kb * 16 + j * 8 + hi * 4;
                        {
                            int ro = l31 * 33 + kp;
                            u32x4 vw = { lVt[ro], lVt[ro + 1], lVt[ro + 2], lVt[ro + 3] };
                            bf16x8 vf = __builtin_bit_cast(bf16x8, vw);
                            acc0 = __builtin_amdgcn_mfma_f32_32x32x16_bf16(vf, pf, acc0, 0, 0, 0);
                        }
                        {
                            int ro = (32 + l31) * 33 + kp;
                            u32x4 vw = { lVt[ro], lVt[ro + 1], lVt[ro + 2], lVt[ro + 3] };
                            bf16x8 vf = __builtin_bit_cast(bf16x8, vw);
                            acc1 = __builtin_amdgcn_mfma_f32_32x32x16_bf16(vf, pf, acc1, 0, 0, 0);
                        }
                    }
                }
            }
            __syncthreads();
        }

        // ---- epilogue: ctx[b][t=qrow][h*64 + dh], dh = dhtile*32 + 8g + 4hi + e
        float inv = 1.0f / lsum;
        size_t orow = ((size_t)(b * 2048 + qrow)) * 1024 + h * 64;
#pragma unroll
        for (int g = 0; g < 4; ++g) {
            us4 o0 = { f2bf(acc0[4 * g] * inv),     f2bf(acc0[4 * g + 1] * inv),
                       f2bf(acc0[4 * g + 2] * inv), f2bf(acc0[4 * g + 3] * inv) };
            *reinterpret_cast<us4*>(&ctx[orow + 8 * g + 4 * hi]) = o0;
            us4 o1 = { f2bf(acc1[4 * g] * inv),     f2bf(acc1[4 * g + 1] * inv),
                       f2bf(acc1[4 * g + 2] * inv), f2bf(acc1[4 * g + 3] * inv) };
            *reinterpret_cast<us4*>(&ctx[orow + 32 + 8 * g + 4 * hi]) = o1;
        }
    }
}

// ---------------------------------------------------------------- out GEMM (+bias, f32 out)
__global__ __launch_bounds__(256) void k_gemm_out(
    const ushort_t* __restrict__ cb, const ushort_t* __restrict__ wot,
    const float* __restrict__ bO, float* __restrict__ out) {
    __shared__ ushort_t lA[128 * 32];
    __shared__ ushort_t lB[128 * 32];
    const int tid = threadIdx.x, wid = tid >> 6, lane = tid & 63;
    const int lr = lane & 15, lg = lane >> 4;
    const int wm = wid >> 1, wn = wid & 1;
    const int bx = blockIdx.x;
    const int by = blockIdx.y;
    const int row0 = by * 128, col0 = bx * 128;
    const int crow = lane >> 2;
    const int coff = (lane & 3) * 8;

    f32x4 acc[4][4] = {};

    for (int k0 = 0; k0 < 1024; k0 += 32) {
        for (int c = wid; c < 8; c += 4) {
            const ushort_t* ga = cb + (size_t)(row0 + c * 16 + crow) * 1024 + k0 + coff;
            __builtin_amdgcn_global_load_lds((const AS1 void*)ga, (AS3 void*)(lA + c * 512), 16, 0, 0);
            const ushort_t* gb = wot + (size_t)(col0 + c * 16 + crow) * 1024 + k0 + coff;
            __builtin_amdgcn_global_load_lds((const AS1 void*)gb, (AS3 void*)(lB + c * 512), 16, 0, 0);
        }
        __syncthreads();
        bf16x8 af[4], bfr[4];
#pragma unroll
        for (int i = 0; i < 4; ++i) {
            af[i]  = *reinterpret_cast<const bf16x8*>(lA + (wm * 64 + i * 16 + lr) * 32 + lg * 8);
            bfr[i] = *reinterpret_cast<const bf16x8*>(lB + (wn * 64 + i * 16 + lr) * 32 + lg * 8);
        }
#pragma unroll
        for (int mi = 0; mi < 4; ++mi)
#pragma unroll
            for (int ni = 0; ni < 4; ++ni)
                acc[mi][ni] = __builtin_amdgcn_mfma_f32_16x16x32_bf16(af[mi], bfr[ni], acc[mi][ni], 0, 0, 0);
        __syncthreads();
    }

#pragma unroll
    for (int mi = 0; mi < 4; ++mi) {
#pragma unroll
        for (int ni = 0; ni < 4; ++ni) {
            int col = col0 + wn * 64 + ni * 16 + lr;
            float bias = bO[col];
#pragma unroll
            for (int e = 0; e < 4; ++e) {
                int row = row0 + wm * 64 + mi * 16 + lg * 4 + e;
                out[(size_t)row * 1024 + col] = acc[mi][ni][e] + bias;
            }
        }
    }
}

// ---------------------------------------------------------------- launch
extern "C" void kernel_launch(void* const* d_in, const int* in_sizes, int n_in,
                              void* d_out, int out_size, void* d_ws, size_t ws_size,
                              hipStream_t stream) {
    const float* x  = (const float*)d_in[0];
    const float* wq = (const float*)d_in[1];
    const float* wk = (const float*)d_in[2];
    const float* wv = (const float*)d_in[3];
    const float* wo = (const float*)d_in[4];
    const float* bo = (const float*)d_in[5];
    float* out = (float*)d_out;

    char* ws = (char*)d_ws;
    ushort_t* xb    = (ushort_t*)(ws);                 // 16 MB   x bf16 [8192][1024]
    ushort_t* wqkvt = (ushort_t*)(ws + 16777216);      // 6 MB    [3][1024 n][1024 k]
    ushort_t* wot   = (ushort_t*)(ws + 23068672);      // 2 MB    [1024 n][1024 k]
    ushort_t* qd    = (ushort_t*)(ws + 25165824);      // 16 MB   [B,H,T,Dh]
    ushort_t* kd    = (ushort_t*)(ws + 41943040);      // 16 MB
    ushort_t* vd    = (ushort_t*)(ws + 58720256);      // 16 MB
    ushort_t* cd    = (ushort_t*)(ws + 75497472);      // 16 MB   ctx bf16 [8192][1024]

    k_convert_x<<<2048, 256, 0, stream>>>(x, xb, 8192 * 1024 / 4);
    k_transpose_w<<<1024, 256, 0, stream>>>(wq, wk, wv, wo, wqkvt, wot);
    k_gemm_qkv<<<dim3(24, 64), 256, 0, stream>>>(xb, wqkvt, qd, kd, vd);
    k_attn<<<512, 256, 0, stream>>>(qd, kd, vd, cd);
    k_gemm_out<<<dim3(8, 64), 256, 0, stream>>>(cd, wot, bo, out);
}

// Round 3
// 191.690 us; speedup vs baseline: 2.1559x; 1.1554x over previous
//
#include <hip/hip_runtime.h>

typedef unsigned short ushort_t;
typedef __attribute__((ext_vector_type(8))) __bf16 bf16x8;
typedef __attribute__((ext_vector_type(4))) float f32x4;
typedef __attribute__((ext_vector_type(16))) float f32x16;
typedef __attribute__((ext_vector_type(4))) unsigned short us4;
typedef __attribute__((ext_vector_type(8))) unsigned short us8;
typedef __attribute__((ext_vector_type(4))) unsigned int u32x4;

#define AS1 __attribute__((address_space(1)))
#define AS3 __attribute__((address_space(3)))

__device__ __forceinline__ unsigned short f2bf(float f) {
    unsigned u = __float_as_uint(f);
    u += 0x7fff + ((u >> 16) & 1);   // RNE
    return (unsigned short)(u >> 16);
}

__device__ __forceinline__ unsigned cvtpk_bf16(float lo, float hi) {
    unsigned r;
    asm("v_cvt_pk_bf16_f32 %0, %1, %2" : "=v"(r) : "v"(lo), "v"(hi));
    return r;
}

__device__ __forceinline__ float fast_exp2(float x) {
    float r;
    asm("v_exp_f32 %0, %1" : "=v"(r) : "v"(x));
    return r;
}

// ---------------------------------------------------------------- convert x
__global__ void k_convert_x(const float* __restrict__ x, ushort_t* __restrict__ xb, int n4) {
    int i = blockIdx.x * blockDim.x + threadIdx.x;
    int stride = gridDim.x * blockDim.x;
    for (; i < n4; i += stride) {
        float4 f = reinterpret_cast<const float4*>(x)[i];
        us4 o = { f2bf(f.x), f2bf(f.y), f2bf(f.z), f2bf(f.w) };
        reinterpret_cast<us4*>(xb)[i] = o;
    }
}

// ------------------------------------------------- transpose weights -> bf16 [n][k]
__global__ void k_transpose_w(const float* __restrict__ wq, const float* __restrict__ wk,
                              const float* __restrict__ wv, const float* __restrict__ wo,
                              ushort_t* __restrict__ wqkvt, ushort_t* __restrict__ wot) {
    __shared__ float t[64][65];
    int bx = blockIdx.x;
    int w = bx >> 8;            // 0..3 : WQ WK WV WO
    int ti = bx & 255;
    int k0 = (ti >> 4) * 64, n0 = (ti & 15) * 64;
    const float* src = (w == 0) ? wq : (w == 1) ? wk : (w == 2) ? wv : wo;
    ushort_t* dst = (w < 3) ? (wqkvt + (size_t)w * 1048576) : wot;
    for (int i = threadIdx.x; i < 4096; i += 256) {
        int r = i >> 6, c = i & 63;
        t[c][r] = src[(size_t)(k0 + r) * 1024 + n0 + c];
    }
    __syncthreads();
    for (int i = threadIdx.x; i < 4096; i += 256) {
        int r = i >> 6, c = i & 63;
        dst[(size_t)(n0 + r) * 1024 + k0 + c] = f2bf(t[r][c]);
    }
}

// ---------------------------------------------------------------- QKV GEMM
// Q output is PRE-SCALED by 0.125*log2(e) so attention softmax runs in exp2 domain.
__global__ __launch_bounds__(256) void k_gemm_qkv(
    const ushort_t* __restrict__ xb, const ushort_t* __restrict__ wt,
    ushort_t* __restrict__ qd, ushort_t* __restrict__ kd, ushort_t* __restrict__ vd) {
    __shared__ ushort_t lA[128 * 32];
    __shared__ ushort_t lB[128 * 32];
    const int tid = threadIdx.x, wid = tid >> 6, lane = tid & 63;
    const int lr = lane & 15, lg = lane >> 4;
    const int wm = wid >> 1, wn = wid & 1;
    const int bx = blockIdx.x;   // 24 col tiles
    const int by = blockIdx.y;   // 64 row tiles
    const int row0 = by * 128, col0 = bx * 128;
    const int crow = lane >> 2;
    const int coff = (lane & 3) * 8;

    f32x4 acc[4][4] = {};

    for (int k0 = 0; k0 < 1024; k0 += 32) {
        for (int c = wid; c < 8; c += 4) {
            const ushort_t* ga = xb + (size_t)(row0 + c * 16 + crow) * 1024 + k0 + coff;
            __builtin_amdgcn_global_load_lds((const AS1 void*)ga, (AS3 void*)(lA + c * 512), 16, 0, 0);
            const ushort_t* gb = wt + (size_t)(col0 + c * 16 + crow) * 1024 + k0 + coff;
            __builtin_amdgcn_global_load_lds((const AS1 void*)gb, (AS3 void*)(lB + c * 512), 16, 0, 0);
        }
        __syncthreads();
        bf16x8 af[4], bfr[4];
#pragma unroll
        for (int i = 0; i < 4; ++i) {
            af[i]  = *reinterpret_cast<const bf16x8*>(lA + (wm * 64 + i * 16 + lr) * 32 + lg * 8);
            bfr[i] = *reinterpret_cast<const bf16x8*>(lB + (wn * 64 + i * 16 + lr) * 32 + lg * 8);
        }
#pragma unroll
        for (int mi = 0; mi < 4; ++mi)
#pragma unroll
            for (int ni = 0; ni < 4; ++ni)
                acc[mi][ni] = __builtin_amdgcn_mfma_f32_16x16x32_bf16(af[mi], bfr[ni], acc[mi][ni], 0, 0, 0);
        __syncthreads();
    }

    const int w = bx >> 3;  // 0:Q 1:K 2:V (uniform per block)
    ushort_t* dst = (w == 0) ? qd : (w == 1) ? kd : vd;
    const float osc = (w == 0) ? 0.18033688f : 1.0f;   // 0.125*log2(e) for Q
#pragma unroll
    for (int mi = 0; mi < 4; ++mi) {
#pragma unroll
        for (int ni = 0; ni < 4; ++ni) {
            int col = col0 + wn * 64 + ni * 16 + lr;
            int c1 = col & 1023;
            int h = c1 >> 6, dh = c1 & 63;
#pragma unroll
            for (int e = 0; e < 4; ++e) {
                int row = row0 + wm * 64 + mi * 16 + lg * 4 + e;
                int b = row >> 11, t = row & 2047;
                dst[(((size_t)(b * 16 + h)) * 2048 + t) * 64 + dh] = f2bf(acc[mi][ni][e] * osc);
            }
        }
    }
}

// ---------------------------------------------------------------- V transpose [bh][t][dh] -> [bh][dh][t]
__global__ __launch_bounds__(256) void k_transpose_v(const ushort_t* __restrict__ vd,
                                                     ushort_t* __restrict__ vt) {
    __shared__ __attribute__((aligned(16))) ushort_t tile[64 * 72];  // col ^= ((t>>3)&7)<<3
    int bid = blockIdx.x;            // 64 bh x 32 ttiles
    int bh = bid >> 5, tt = bid & 31;
    const ushort_t* src = vd + ((size_t)bh * 2048 + tt * 64) * 64;
    ushort_t* dst = vt + (size_t)bh * 2048 * 64 + tt * 64;
#pragma unroll
    for (int r = 0; r < 2; ++r) {
        int i = r * 256 + threadIdx.x;
        int t = i >> 3, c8 = (i & 7) * 8;
        us8 v = *reinterpret_cast<const us8*>(src + (size_t)t * 64 + c8);
        *reinterpret_cast<us8*>(&tile[t * 72 + (c8 ^ ((t >> 3) << 3))]) = v;
    }
    __syncthreads();
#pragma unroll
    for (int r = 0; r < 2; ++r) {
        int i = r * 256 + threadIdx.x;
        int dh = i >> 3, t8 = (i & 7) * 8;
        us8 o;
#pragma unroll
        for (int e = 0; e < 8; ++e)
            o[e] = tile[(t8 + e) * 72 + (dh ^ ((t8 >> 3) << 3))];
        *reinterpret_cast<us8*>(dst + (size_t)dh * 2048 + t8) = o;
    }
}

// ---------------------------------------------------------------- attention
// 4 waves x 32 q-rows = 128-row q-tile per block; 1024 blocks, big-tiles-first.
// Swapped QK^T (S^T = K x Q), lane owns P-row for q = lane&31; ctx^T = V^T x P^T.
// K and V^T staged via global_load_lds (linear dest) with pre-swizzled source
// (byte ^= (row&7)<<4), double-buffered, one barrier per KV tile.
__global__ __launch_bounds__(256) void k_attn(
    const ushort_t* __restrict__ q, const ushort_t* __restrict__ k,
    const ushort_t* __restrict__ v, ushort_t* __restrict__ ctx) {
    __shared__ __attribute__((aligned(16))) ushort_t lsK[2 * 4096];  // 2 x [64 key][64 dh]
    __shared__ __attribute__((aligned(16))) ushort_t lsV[2 * 4096];  // 2 x [64 dh][64 key]

    const int tid = threadIdx.x, wid = tid >> 6, lane = tid & 63;
    const int l31 = lane & 31, hi = lane >> 5;
    const int bid = blockIdx.x;
    const int bh = bid & 63;
    const int qt = 15 - (bid >> 6);          // big tiles dispatched first
    const int q0 = qt * 128;
    const int q0w = q0 + wid * 32;
    const int qrow = q0w + l31;
    const int njt = (q0 >> 6) + 2;

    const size_t base = (size_t)bh * 2048 * 64;
    const ushort_t* qg = q + base;
    const ushort_t* kg = k + base;
    const ushort_t* vtg = v + base;          // [dh][t]
    const int b = bh >> 4, h = bh & 15;

    // Q fragments (already scaled by 0.125*log2e)
    bf16x8 qf[4];
#pragma unroll
    for (int s = 0; s < 4; ++s)
        qf[s] = *reinterpret_cast<const bf16x8*>(qg + (size_t)qrow * 64 + s * 16 + hi * 8);

    // staging lane constants
    const int skey = wid * 8 + (lane >> 3);             // row for r=0 (r=1 adds 32)
    const int scb0 = ((lane & 7) * 16) ^ ((skey & 7) << 4);  // swizzled byte-in-row (row&7 same for +32)

    // frag read byte offsets (loop-invariant)
    const int kx = (l31 & 7) << 4;
    int koffA[4], voffA[4];
#pragma unroll
    for (int s = 0; s < 4; ++s) {
        koffA[s] = l31 * 128 + ((s * 32 + hi * 16) ^ kx);
        voffA[s] = koffA[s];                 // same formula, used with jj index
    }

    auto stage = [&](int j0, int bufb) {
#pragma unroll
        for (int r = 0; r < 2; ++r) {
            int row = skey + r * 32;
            const ushort_t* ks = kg + (size_t)(j0 + row) * 64 + (scb0 >> 1);
            __builtin_amdgcn_global_load_lds((const AS1 void*)ks,
                (AS3 void*)((AS3 char*)lsK + bufb + r * 4096 + wid * 1024), 16, 0, 0);
            const ushort_t* vs = vtg + (size_t)row * 2048 + j0 + (scb0 >> 1);
            __builtin_amdgcn_global_load_lds((const AS1 void*)vs,
                (AS3 void*)((AS3 char*)lsV + bufb + r * 4096 + wid * 1024), 16, 0, 0);
        }
    };

    f32x16 acc0 = {}, acc1 = {};
    float m = -1e30f, lsum = 0.f;

    stage(0, 0);
    for (int jt = 0; jt < njt; ++jt) {
        __syncthreads();                               // tile jt ready (drains vmcnt)
        const int j0 = jt << 6;
        if (jt + 1 < njt) stage(j0 + 64, ((jt + 1) & 1) * 8192);

        if (j0 < q0w + 32) {
            const char* bK = reinterpret_cast<const char*>(lsK) + (jt & 1) * 8192;
            const char* bV = reinterpret_cast<const char*>(lsV) + (jt & 1) * 8192;

            // ---- S^T = K x Q
            f32x16 s0 = {}, s1 = {};
#pragma unroll
            for (int s = 0; s < 4; ++s) {
                bf16x8 ka = *reinterpret_cast<const bf16x8*>(bK + koffA[s]);
                s0 = __builtin_amdgcn_mfma_f32_32x32x16_bf16(ka, qf[s], s0, 0, 0, 0);
            }
#pragma unroll
            for (int s = 0; s < 4; ++s) {
                bf16x8 ka = *reinterpret_cast<const bf16x8*>(bK + 4096 + koffA[s]);
                s1 = __builtin_amdgcn_mfma_f32_32x32x16_bf16(ka, qf[s], s1, 0, 0, 0);
            }

            // ---- causal mask (scores already in exp2 domain)
            float p0[16], p1[16];
            const bool needmask = (j0 + 63 > q0w);
#pragma unroll
            for (int r = 0; r < 16; ++r) {
                float a = s0[r], c = s1[r];
                if (needmask) {
                    int kl = j0 + (r & 3) + 8 * (r >> 2) + 4 * hi;
                    if (kl > qrow) a = -1e30f;
                    if (kl + 32 > qrow) c = -1e30f;
                }
                p0[r] = a; p1[r] = c;
            }

            // ---- online softmax (defer-max, THR=8 in log2 units)
            float mx = p0[0];
#pragma unroll
            for (int r = 1; r < 16; ++r) mx = fmaxf(mx, p0[r]);
#pragma unroll
            for (int r = 0; r < 16; ++r) mx = fmaxf(mx, p1[r]);
            mx = fmaxf(mx, __shfl_xor(mx, 32));
            if (__ballot(mx > m + 8.0f)) {
                float mnew = fmaxf(m, mx);
                float scl = fast_exp2(m - mnew);
                m = mnew;
                lsum *= scl;
#pragma unroll
                for (int r = 0; r < 16; ++r) { acc0[r] *= scl; acc1[r] *= scl; }
            }
            float rs = 0.f;
#pragma unroll
            for (int r = 0; r < 16; ++r) {
                float e0 = fast_exp2(p0[r] - m); p0[r] = e0;
                float e1 = fast_exp2(p1[r] - m); p1[r] = e1;
                rs += e0 + e1;
            }
            rs += __shfl_xor(rs, 32);
            lsum += rs;

            // ---- P pack (permlane32_swap builds both fragment words per swap)
#pragma unroll
            for (int kb = 0; kb < 2; ++kb) {
                const float* pp = kb ? p1 : p0;
                unsigned pw[8];
#pragma unroll
                for (int g = 0; g < 4; ++g) {
                    pw[2 * g]     = cvtpk_bf16(pp[4 * g],     pp[4 * g + 1]);
                    pw[2 * g + 1] = cvtpk_bf16(pp[4 * g + 2], pp[4 * g + 3]);
                }
#pragma unroll
                for (int j = 0; j < 2; ++j) {
                    asm("v_permlane32_swap_b32 %0, %1" : "+v"(pw[4 * j]),     "+v"(pw[4 * j + 2]));
                    asm("v_permlane32_swap_b32 %0, %1" : "+v"(pw[4 * j + 1]), "+v"(pw[4 * j + 3]));
                    u32x4 fw = { pw[4 * j], pw[4 * j + 1], pw[4 * j + 2], pw[4 * j + 3] };
                    bf16x8 pf = __builtin_bit_cast(bf16x8, fw);
                    int jj = kb * 2 + j;
                    {
                        bf16x8 vf = *reinterpret_cast<const bf16x8*>(
                            bV + (l31 * 128 + ((jj * 32 + hi * 16) ^ kx)));
                        acc0 = __builtin_amdgcn_mfma_f32_32x32x16_bf16(vf, pf, acc0, 0, 0, 0);
                    }
                    {
                        bf16x8 vf = *reinterpret_cast<const bf16x8*>(
                            bV + 4096 + (l31 * 128 + ((jj * 32 + hi * 16) ^ kx)));
                        acc1 = __builtin_amdgcn_mfma_f32_32x32x16_bf16(vf, pf, acc1, 0, 0, 0);
                    }
                }
            }
        }
    }

    // ---- epilogue: ctx[b][t=qrow][h*64 + dh]
    float inv = 1.0f / lsum;
    size_t orow = ((size_t)(b * 2048 + qrow)) * 1024 + h * 64;
#pragma unroll
    for (int g = 0; g < 4; ++g) {
        us4 o0 = { f2bf(acc0[4 * g] * inv),     f2bf(acc0[4 * g + 1] * inv),
                   f2bf(acc0[4 * g + 2] * inv), f2bf(acc0[4 * g + 3] * inv) };
        *reinterpret_cast<us4*>(&ctx[orow + 8 * g + 4 * hi]) = o0;
        us4 o1 = { f2bf(acc1[4 * g] * inv),     f2bf(acc1[4 * g + 1] * inv),
                   f2bf(acc1[4 * g + 2] * inv), f2bf(acc1[4 * g + 3] * inv) };
        *reinterpret_cast<us4*>(&ctx[orow + 32 + 8 * g + 4 * hi]) = o1;
    }
}

// ---------------------------------------------------------------- out GEMM (+bias, f32 out)
__global__ __launch_bounds__(256) void k_gemm_out(
    const ushort_t* __restrict__ cb, const ushort_t* __restrict__ wot,
    const float* __restrict__ bO, float* __restrict__ out) {
    __shared__ ushort_t lA[128 * 32];
    __shared__ ushort_t lB[128 * 32];
    const int tid = threadIdx.x, wid = tid >> 6, lane = tid & 63;
    const int lr = lane & 15, lg = lane >> 4;
    const int wm = wid >> 1, wn = wid & 1;
    const int bx = blockIdx.x;
    const int by = blockIdx.y;
    const int row0 = by * 128, col0 = bx * 128;
    const int crow = lane >> 2;
    const int coff = (lane & 3) * 8;

    f32x4 acc[4][4] = {};

    for (int k0 = 0; k0 < 1024; k0 += 32) {
        for (int c = wid; c < 8; c += 4) {
            const ushort_t* ga = cb + (size_t)(row0 + c * 16 + crow) * 1024 + k0 + coff;
            __builtin_amdgcn_global_load_lds((const AS1 void*)ga, (AS3 void*)(lA + c * 512), 16, 0, 0);
            const ushort_t* gb = wot + (size_t)(col0 + c * 16 + crow) * 1024 + k0 + coff;
            __builtin_amdgcn_global_load_lds((const AS1 void*)gb, (AS3 void*)(lB + c * 512), 16, 0, 0);
        }
        __syncthreads();
        bf16x8 af[4], bfr[4];
#pragma unroll
        for (int i = 0; i < 4; ++i) {
            af[i]  = *reinterpret_cast<const bf16x8*>(lA + (wm * 64 + i * 16 + lr) * 32 + lg * 8);
            bfr[i] = *reinterpret_cast<const bf16x8*>(lB + (wn * 64 + i * 16 + lr) * 32 + lg * 8);
        }
#pragma unroll
        for (int mi = 0; mi < 4; ++mi)
#pragma unroll
            for (int ni = 0; ni < 4; ++ni)
                acc[mi][ni] = __builtin_amdgcn_mfma_f32_16x16x32_bf16(af[mi], bfr[ni], acc[mi][ni], 0, 0, 0);
        __syncthreads();
    }

#pragma unroll
    for (int mi = 0; mi < 4; ++mi) {
#pragma unroll
        for (int ni = 0; ni < 4; ++ni) {
            int col = col0 + wn * 64 + ni * 16 + lr;
            float bias = bO[col];
#pragma unroll
            for (int e = 0; e < 4; ++e) {
                int row = row0 + wm * 64 + mi * 16 + lg * 4 + e;
                out[(size_t)row * 1024 + col] = acc[mi][ni][e] + bias;
            }
        }
    }
}

// ---------------------------------------------------------------- launch
extern "C" void kernel_launch(void* const* d_in, const int* in_sizes, int n_in,
                              void* d_out, int out_size, void* d_ws, size_t ws_size,
                              hipStream_t stream) {
    const float* x  = (const float*)d_in[0];
    const float* wq = (const float*)d_in[1];
    const float* wk = (const float*)d_in[2];
    const float* wv = (const float*)d_in[3];
    const float* wo = (const float*)d_in[4];
    const float* bo = (const float*)d_in[5];
    float* out = (float*)d_out;

    char* ws = (char*)d_ws;
    ushort_t* xb    = (ushort_t*)(ws);                 // 16 MB   x bf16 [8192][1024]; reused as V^T after gemm
    ushort_t* wqkvt = (ushort_t*)(ws + 16777216);      // 6 MB    [3][1024 n][1024 k]
    ushort_t* wot   = (ushort_t*)(ws + 23068672);      // 2 MB    [1024 n][1024 k]
    ushort_t* qd    = (ushort_t*)(ws + 25165824);      // 16 MB   [B,H,T,Dh] (pre-scaled)
    ushort_t* kd    = (ushort_t*)(ws + 41943040);      // 16 MB   [B,H,T,Dh]
    ushort_t* vd    = (ushort_t*)(ws + 58720256);      // 16 MB   [B,H,T,Dh]
    ushort_t* cd    = (ushort_t*)(ws + 75497472);      // 16 MB   ctx bf16 [8192][1024]
    ushort_t* vt    = xb;                              // V^T [B,H,Dh,T] (xb dead after gemm_qkv)

    k_convert_x<<<2048, 256, 0, stream>>>(x, xb, 8192 * 1024 / 4);
    k_transpose_w<<<1024, 256, 0, stream>>>(wq, wk, wv, wo, wqkvt, wot);
    k_gemm_qkv<<<dim3(24, 64), 256, 0, stream>>>(xb, wqkvt, qd, kd, vd);
    k_transpose_v<<<2048, 256, 0, stream>>>(vd, vt);
    k_attn<<<1024, 256, 0, stream>>>(qd, kd, vt, cd);
    k_gemm_out<<<dim3(8, 64), 256, 0, stream>>>(cd, wot, bo, out);
}

// Round 4
// 176.910 us; speedup vs baseline: 2.3360x; 1.0835x over previous
//
#include <hip/hip_runtime.h>

typedef unsigned short ushort_t;
typedef __attribute__((ext_vector_type(8))) __bf16 bf16x8;
typedef __attribute__((ext_vector_type(4))) float f32x4;
typedef __attribute__((ext_vector_type(16))) float f32x16;
typedef __attribute__((ext_vector_type(4))) unsigned short us4;
typedef __attribute__((ext_vector_type(8))) unsigned short us8;
typedef __attribute__((ext_vector_type(4))) unsigned int u32x4;

#define AS1 __attribute__((address_space(1)))
#define AS3 __attribute__((address_space(3)))

__device__ __forceinline__ unsigned short f2bf(float f) {
    unsigned u = __float_as_uint(f);
    u += 0x7fff + ((u >> 16) & 1);   // RNE
    return (unsigned short)(u >> 16);
}

__device__ __forceinline__ unsigned cvtpk_bf16(float lo, float hi) {
    unsigned r;
    asm("v_cvt_pk_bf16_f32 %0, %1, %2" : "=v"(r) : "v"(lo), "v"(hi));
    return r;
}

__device__ __forceinline__ float fast_exp2(float x) {
    float r;
    asm("v_exp_f32 %0, %1" : "=v"(r) : "v"(x));
    return r;
}

// ---------------------------------------------------------------- convert x
__global__ void k_convert_x(const float* __restrict__ x, ushort_t* __restrict__ xb, int n4) {
    int i = blockIdx.x * blockDim.x + threadIdx.x;
    int stride = gridDim.x * blockDim.x;
    for (; i < n4; i += stride) {
        float4 f = reinterpret_cast<const float4*>(x)[i];
        us4 o = { f2bf(f.x), f2bf(f.y), f2bf(f.z), f2bf(f.w) };
        reinterpret_cast<us4*>(xb)[i] = o;
    }
}

// ------------------------------------------------- transpose weights -> bf16 [n][k]
__global__ void k_transpose_w(const float* __restrict__ wq, const float* __restrict__ wk,
                              const float* __restrict__ wv, const float* __restrict__ wo,
                              ushort_t* __restrict__ wqkvt, ushort_t* __restrict__ wot) {
    __shared__ float t[64][65];
    int bx = blockIdx.x;
    int w = bx >> 8;            // 0..3 : WQ WK WV WO
    int ti = bx & 255;
    int k0 = (ti >> 4) * 64, n0 = (ti & 15) * 64;
    const float* src = (w == 0) ? wq : (w == 1) ? wk : (w == 2) ? wv : wo;
    ushort_t* dst = (w < 3) ? (wqkvt + (size_t)w * 1048576) : wot;
    for (int i = threadIdx.x; i < 4096; i += 256) {
        int r = i >> 6, c = i & 63;
        t[c][r] = src[(size_t)(k0 + r) * 1024 + n0 + c];
    }
    __syncthreads();
    for (int i = threadIdx.x; i < 4096; i += 256) {
        int r = i >> 6, c = i & 63;
        dst[(size_t)(n0 + r) * 1024 + k0 + c] = f2bf(t[r][c]);
    }
}

// ---------------------------------------------------------------- QKV GEMM
// Q output is PRE-SCALED by 0.125*log2(e) so attention softmax runs in exp2 domain.
__global__ __launch_bounds__(256) void k_gemm_qkv(
    const ushort_t* __restrict__ xb, const ushort_t* __restrict__ wt,
    ushort_t* __restrict__ qd, ushort_t* __restrict__ kd, ushort_t* __restrict__ vd) {
    __shared__ ushort_t lA[128 * 32];
    __shared__ ushort_t lB[128 * 32];
    const int tid = threadIdx.x, wid = tid >> 6, lane = tid & 63;
    const int lr = lane & 15, lg = lane >> 4;
    const int wm = wid >> 1, wn = wid & 1;
    const int bx = blockIdx.x;   // 24 col tiles
    const int by = blockIdx.y;   // 64 row tiles
    const int row0 = by * 128, col0 = bx * 128;
    const int crow = lane >> 2;
    const int coff = (lane & 3) * 8;

    f32x4 acc[4][4] = {};

    for (int k0 = 0; k0 < 1024; k0 += 32) {
        for (int c = wid; c < 8; c += 4) {
            const ushort_t* ga = xb + (size_t)(row0 + c * 16 + crow) * 1024 + k0 + coff;
            __builtin_amdgcn_global_load_lds((const AS1 void*)ga, (AS3 void*)(lA + c * 512), 16, 0, 0);
            const ushort_t* gb = wt + (size_t)(col0 + c * 16 + crow) * 1024 + k0 + coff;
            __builtin_amdgcn_global_load_lds((const AS1 void*)gb, (AS3 void*)(lB + c * 512), 16, 0, 0);
        }
        __syncthreads();
        bf16x8 af[4], bfr[4];
#pragma unroll
        for (int i = 0; i < 4; ++i) {
            af[i]  = *reinterpret_cast<const bf16x8*>(lA + (wm * 64 + i * 16 + lr) * 32 + lg * 8);
            bfr[i] = *reinterpret_cast<const bf16x8*>(lB + (wn * 64 + i * 16 + lr) * 32 + lg * 8);
        }
#pragma unroll
        for (int mi = 0; mi < 4; ++mi)
#pragma unroll
            for (int ni = 0; ni < 4; ++ni)
                acc[mi][ni] = __builtin_amdgcn_mfma_f32_16x16x32_bf16(af[mi], bfr[ni], acc[mi][ni], 0, 0, 0);
        __syncthreads();
    }

    const int w = bx >> 3;  // 0:Q 1:K 2:V (uniform per block)
    ushort_t* dst = (w == 0) ? qd : (w == 1) ? kd : vd;
    const float osc = (w == 0) ? 0.18033688f : 1.0f;   // 0.125*log2(e) for Q
#pragma unroll
    for (int mi = 0; mi < 4; ++mi) {
#pragma unroll
        for (int ni = 0; ni < 4; ++ni) {
            int col = col0 + wn * 64 + ni * 16 + lr;
            int c1 = col & 1023;
            int h = c1 >> 6, dh = c1 & 63;
#pragma unroll
            for (int e = 0; e < 4; ++e) {
                int row = row0 + wm * 64 + mi * 16 + lg * 4 + e;
                int b = row >> 11, t = row & 2047;
                dst[(((size_t)(b * 16 + h)) * 2048 + t) * 64 + dh] = f2bf(acc[mi][ni][e] * osc);
            }
        }
    }
}

// ---------------------------------------------------------------- V transpose [bh][t][dh] -> [bh][dh][t]
__global__ __launch_bounds__(256) void k_transpose_v(const ushort_t* __restrict__ vd,
                                                     ushort_t* __restrict__ vt) {
    __shared__ __attribute__((aligned(16))) ushort_t tile[64 * 72];  // col ^= ((t>>3)&7)<<3
    int bid = blockIdx.x;            // 64 bh x 32 ttiles
    int bh = bid >> 5, tt = bid & 31;
    const ushort_t* src = vd + ((size_t)bh * 2048 + tt * 64) * 64;
    ushort_t* dst = vt + (size_t)bh * 2048 * 64 + tt * 64;
#pragma unroll
    for (int r = 0; r < 2; ++r) {
        int i = r * 256 + threadIdx.x;
        int t = i >> 3, c8 = (i & 7) * 8;
        us8 v = *reinterpret_cast<const us8*>(src + (size_t)t * 64 + c8);
        *reinterpret_cast<us8*>(&tile[t * 72 + (c8 ^ ((t >> 3) << 3))]) = v;
    }
    __syncthreads();
#pragma unroll
    for (int r = 0; r < 2; ++r) {
        int i = r * 256 + threadIdx.x;
        int dh = i >> 3, t8 = (i & 7) * 8;
        us8 o;
#pragma unroll
        for (int e = 0; e < 8; ++e)
            o[e] = tile[(t8 + e) * 72 + (dh ^ ((t8 >> 3) << 3))];
        *reinterpret_cast<us8*>(dst + (size_t)dh * 2048 + t8) = o;
    }
}

// ---------------------------------------------------------------- attention
// 512 blocks: 64 bh x 8 pair-index; pass 0 handles q-tile 15-pi (big), pass 1 handles pi
// -> uniform 17 KV-128 iterations per block. 4 waves x 32 q-rows.
// Swapped QK^T (S^T = K x Q) in exp2 domain with NO max tracking (scores bounded);
// ctx^T = V^T x P^T; row-sum via MFMA with A=ones. KV staged 128 keys/barrier,
// double-buffered (64KB), global_load_lds w16 with pre-swizzled source.
__global__ __launch_bounds__(256) void k_attn(
    const ushort_t* __restrict__ q, const ushort_t* __restrict__ k,
    const ushort_t* __restrict__ v, ushort_t* __restrict__ ctx) {
    __shared__ __attribute__((aligned(16))) ushort_t lsK[2 * 8192];  // 2 bufs x [2][64 key][64 dh]
    __shared__ __attribute__((aligned(16))) ushort_t lsV[2 * 8192];  // 2 bufs x [2][64 dh][64 key]

    const int tid = threadIdx.x, wid = tid >> 6, lane = tid & 63;
    const int l31 = lane & 31, hi = lane >> 5;
    const int bid = blockIdx.x;
    const int bh = bid >> 3, pi = bid & 7;
    const size_t base = (size_t)bh * 2048 * 64;
    const ushort_t* qg = q + base;
    const ushort_t* kg = k + base;
    const ushort_t* vtg = v + base;          // [dh][t]
    const int b = bh >> 4, h = bh & 15;

    const int skey = wid * 8 + (lane >> 3);
    const int scb0 = ((lane & 7) * 16) ^ ((skey & 7) << 4);  // swizzled byte-in-row
    const int kx = (l31 & 7) << 4;
    int koffA[4];
#pragma unroll
    for (int s = 0; s < 4; ++s)
        koffA[s] = l31 * 128 + ((s * 32 + hi * 16) ^ kx);

    us8 ow;
#pragma unroll
    for (int e = 0; e < 8; ++e) ow[e] = 0x3F80;              // bf16 1.0
    const bf16x8 onef = __builtin_bit_cast(bf16x8, ow);

#pragma unroll 1
    for (int pass = 0; pass < 2; ++pass) {
        const int qt = pass ? pi : (15 - pi);
        const int q0 = qt * 128;
        const int q0w = q0 + wid * 32;
        const int qrow = q0w + l31;
        const int njt = qt + 1;              // 128-key tiles

        bf16x8 qf[4];
#pragma unroll
        for (int s = 0; s < 4; ++s)
            qf[s] = *reinterpret_cast<const bf16x8*>(qg + (size_t)qrow * 64 + s * 16 + hi * 8);

        const ushort_t* kpr[4];
        const ushort_t* vpr[4];
#pragma unroll
        for (int r = 0; r < 4; ++r) {
            kpr[r] = kg + (size_t)(r * 32 + skey) * 64 + (scb0 >> 1);
            vpr[r] = vtg + (size_t)((r & 1) * 32 + skey) * 2048 + (r >> 1) * 64 + (scb0 >> 1);
        }

        f32x16 acc0 = {}, acc1 = {}, lacc = {};

        __syncthreads();                     // protect LDS from previous pass readers
#pragma unroll
        for (int r = 0; r < 4; ++r) {        // stage tile 0 -> buffer 0
            __builtin_amdgcn_global_load_lds((const AS1 void*)kpr[r],
                (AS3 void*)((AS3 char*)lsK + r * 4096 + wid * 1024), 16, 0, 0);
            __builtin_amdgcn_global_load_lds((const AS1 void*)vpr[r],
                (AS3 void*)((AS3 char*)lsV + r * 4096 + wid * 1024), 16, 0, 0);
        }

        unsigned bo = 0;
        for (int jt = 0; jt < njt; ++jt) {
            __syncthreads();                 // tile jt resident (each wave drained own vmcnt)
            const int j0 = jt << 7;
            if (jt + 1 < njt) {
                const unsigned nb = bo ^ 16384;
#pragma unroll
                for (int r = 0; r < 4; ++r) {
                    kpr[r] += 8192;
                    vpr[r] += 128;
                    __builtin_amdgcn_global_load_lds((const AS1 void*)kpr[r],
                        (AS3 void*)((AS3 char*)lsK + nb + r * 4096 + wid * 1024), 16, 0, 0);
                    __builtin_amdgcn_global_load_lds((const AS1 void*)vpr[r],
                        (AS3 void*)((AS3 char*)lsV + nb + r * 4096 + wid * 1024), 16, 0, 0);
                }
            }

#pragma unroll
            for (int hh = 0; hh < 2; ++hh) {
                const int j0h = j0 + hh * 64;
                if (j0h < q0w + 32) {
                    const char* bK = reinterpret_cast<const char*>(lsK) + bo + hh * 8192;
                    const char* bV = reinterpret_cast<const char*>(lsV) + bo + hh * 8192;

                    // ---- S^T = K x Q
                    f32x16 s0 = {}, s1 = {};
#pragma unroll
                    for (int s = 0; s < 4; ++s) {
                        bf16x8 ka = *reinterpret_cast<const bf16x8*>(bK + koffA[s]);
                        s0 = __builtin_amdgcn_mfma_f32_32x32x16_bf16(ka, qf[s], s0, 0, 0, 0);
                    }
#pragma unroll
                    for (int s = 0; s < 4; ++s) {
                        bf16x8 ka = *reinterpret_cast<const bf16x8*>(bK + 4096 + koffA[s]);
                        s1 = __builtin_amdgcn_mfma_f32_32x32x16_bf16(ka, qf[s], s1, 0, 0, 0);
                    }

                    // ---- P = exp2(S) with causal zeroing (no max tracking: scores bounded)
                    float p0[16], p1[16];
                    if (j0h + 63 > q0w) {
                        const int jh = j0h + 4 * hi;
#pragma unroll
                        for (int r = 0; r < 16; ++r) {
                            const int kl = jh + (r & 3) + 8 * (r >> 2);
                            float e0 = fast_exp2(s0[r]);
                            float e1 = fast_exp2(s1[r]);
                            p0[r] = (kl > qrow) ? 0.f : e0;
                            p1[r] = (kl + 32 > qrow) ? 0.f : e1;
                        }
                    } else {
#pragma unroll
                        for (int r = 0; r < 16; ++r) {
                            p0[r] = fast_exp2(s0[r]);
                            p1[r] = fast_exp2(s1[r]);
                        }
                    }

                    // ---- pack P -> bf16 frags; PV and row-sum via MFMA
#pragma unroll
                    for (int kb = 0; kb < 2; ++kb) {
                        const float* pp = kb ? p1 : p0;
                        unsigned pw[8];
#pragma unroll
                        for (int g = 0; g < 4; ++g) {
                            pw[2 * g]     = cvtpk_bf16(pp[4 * g],     pp[4 * g + 1]);
                            pw[2 * g + 1] = cvtpk_bf16(pp[4 * g + 2], pp[4 * g + 3]);
                        }
#pragma unroll
                        for (int j = 0; j < 2; ++j) {
                            asm("v_permlane32_swap_b32 %0, %1" : "+v"(pw[4 * j]),     "+v"(pw[4 * j + 2]));
                            asm("v_permlane32_swap_b32 %0, %1" : "+v"(pw[4 * j + 1]), "+v"(pw[4 * j + 3]));
                            u32x4 fw = { pw[4 * j], pw[4 * j + 1], pw[4 * j + 2], pw[4 * j + 3] };
                            bf16x8 pf = __builtin_bit_cast(bf16x8, fw);
                            const int jj = kb * 2 + j;
                            {
                                bf16x8 vf = *reinterpret_cast<const bf16x8*>(bV + koffA[jj]);
                                acc0 = __builtin_amdgcn_mfma_f32_32x32x16_bf16(vf, pf, acc0, 0, 0, 0);
                            }
                            {
                                bf16x8 vf = *reinterpret_cast<const bf16x8*>(bV + 4096 + koffA[jj]);
                                acc1 = __builtin_amdgcn_mfma_f32_32x32x16_bf16(vf, pf, acc1, 0, 0, 0);
                            }
                            lacc = __builtin_amdgcn_mfma_f32_32x32x16_bf16(onef, pf, lacc, 0, 0, 0);
                        }
                    }
                }
            }
            bo ^= 16384;
        }

        // ---- epilogue: ctx[b][t=qrow][h*64 + dh]
        float inv = 1.0f / lacc[0];
        size_t orow = ((size_t)(b * 2048 + qrow)) * 1024 + h * 64;
#pragma unroll
        for (int g = 0; g < 4; ++g) {
            us4 o0 = { f2bf(acc0[4 * g] * inv),     f2bf(acc0[4 * g + 1] * inv),
                       f2bf(acc0[4 * g + 2] * inv), f2bf(acc0[4 * g + 3] * inv) };
            *reinterpret_cast<us4*>(&ctx[orow + 8 * g + 4 * hi]) = o0;
            us4 o1 = { f2bf(acc1[4 * g] * inv),     f2bf(acc1[4 * g + 1] * inv),
                       f2bf(acc1[4 * g + 2] * inv), f2bf(acc1[4 * g + 3] * inv) };
            *reinterpret_cast<us4*>(&ctx[orow + 32 + 8 * g + 4 * hi]) = o1;
        }
    }
}

// ---------------------------------------------------------------- out GEMM (+bias, f32 out)
__global__ __launch_bounds__(256) void k_gemm_out(
    const ushort_t* __restrict__ cb, const ushort_t* __restrict__ wot,
    const float* __restrict__ bO, float* __restrict__ out) {
    __shared__ ushort_t lA[128 * 32];
    __shared__ ushort_t lB[128 * 32];
    const int tid = threadIdx.x, wid = tid >> 6, lane = tid & 63;
    const int lr = lane & 15, lg = lane >> 4;
    const int wm = wid >> 1, wn = wid & 1;
    const int bx = blockIdx.x;
    const int by = blockIdx.y;
    const int row0 = by * 128, col0 = bx * 128;
    const int crow = lane >> 2;
    const int coff = (lane & 3) * 8;

    f32x4 acc[4][4] = {};

    for (int k0 = 0; k0 < 1024; k0 += 32) {
        for (int c = wid; c < 8; c += 4) {
            const ushort_t* ga = cb + (size_t)(row0 + c * 16 + crow) * 1024 + k0 + coff;
            __builtin_amdgcn_global_load_lds((const AS1 void*)ga, (AS3 void*)(lA + c * 512), 16, 0, 0);
            const ushort_t* gb = wot + (size_t)(col0 + c * 16 + crow) * 1024 + k0 + coff;
            __builtin_amdgcn_global_load_lds((const AS1 void*)gb, (AS3 void*)(lB + c * 512), 16, 0, 0);
        }
        __syncthreads();
        bf16x8 af[4], bfr[4];
#pragma unroll
        for (int i = 0; i < 4; ++i) {
            af[i]  = *reinterpret_cast<const bf16x8*>(lA + (wm * 64 + i * 16 + lr) * 32 + lg * 8);
            bfr[i] = *reinterpret_cast<const bf16x8*>(lB + (wn * 64 + i * 16 + lr) * 32 + lg * 8);
        }
#pragma unroll
        for (int mi = 0; mi < 4; ++mi)
#pragma unroll
            for (int ni = 0; ni < 4; ++ni)
                acc[mi][ni] = __builtin_amdgcn_mfma_f32_16x16x32_bf16(af[mi], bfr[ni], acc[mi][ni], 0, 0, 0);
        __syncthreads();
    }

#pragma unroll
    for (int mi = 0; mi < 4; ++mi) {
#pragma unroll
        for (int ni = 0; ni < 4; ++ni) {
            int col = col0 + wn * 64 + ni * 16 + lr;
            float bias = bO[col];
#pragma unroll
            for (int e = 0; e < 4; ++e) {
                int row = row0 + wm * 64 + mi * 16 + lg * 4 + e;
                out[(size_t)row * 1024 + col] = acc[mi][ni][e] + bias;
            }
        }
    }
}

// ---------------------------------------------------------------- launch
extern "C" void kernel_launch(void* const* d_in, const int* in_sizes, int n_in,
                              void* d_out, int out_size, void* d_ws, size_t ws_size,
                              hipStream_t stream) {
    const float* x  = (const float*)d_in[0];
    const float* wq = (const float*)d_in[1];
    const float* wk = (const float*)d_in[2];
    const float* wv = (const float*)d_in[3];
    const float* wo = (const float*)d_in[4];
    const float* bo = (const float*)d_in[5];
    float* out = (float*)d_out;

    char* ws = (char*)d_ws;
    ushort_t* xb    = (ushort_t*)(ws);                 // 16 MB   x bf16 [8192][1024]; reused as V^T after gemm
    ushort_t* wqkvt = (ushort_t*)(ws + 16777216);      // 6 MB    [3][1024 n][1024 k]
    ushort_t* wot   = (ushort_t*)(ws + 23068672);      // 2 MB    [1024 n][1024 k]
    ushort_t* qd    = (ushort_t*)(ws + 25165824);      // 16 MB   [B,H,T,Dh] (pre-scaled)
    ushort_t* kd    = (ushort_t*)(ws + 41943040);      // 16 MB   [B,H,T,Dh]
    ushort_t* vd    = (ushort_t*)(ws + 58720256);      // 16 MB   [B,H,T,Dh]
    ushort_t* cd    = (ushort_t*)(ws + 75497472);      // 16 MB   ctx bf16 [8192][1024]
    ushort_t* vt    = xb;                              // V^T [B,H,Dh,T] (xb dead after gemm_qkv)

    k_convert_x<<<2048, 256, 0, stream>>>(x, xb, 8192 * 1024 / 4);
    k_transpose_w<<<1024, 256, 0, stream>>>(wq, wk, wv, wo, wqkvt, wot);
    k_gemm_qkv<<<dim3(24, 64), 256, 0, stream>>>(xb, wqkvt, qd, kd, vd);
    k_transpose_v<<<2048, 256, 0, stream>>>(vd, vt);
    k_attn<<<512, 256, 0, stream>>>(qd, kd, vt, cd);
    k_gemm_out<<<dim3(8, 64), 256, 0, stream>>>(cd, wot, bo, out);
}

// Round 5
// 175.074 us; speedup vs baseline: 2.3605x; 1.0105x over previous
//
#include <hip/hip_runtime.h>

typedef unsigned short ushort_t;
typedef __attribute__((ext_vector_type(8))) __bf16 bf16x8;
typedef __attribute__((ext_vector_type(4))) float f32x4;
typedef __attribute__((ext_vector_type(16))) float f32x16;
typedef __attribute__((ext_vector_type(4))) unsigned short us4;
typedef __attribute__((ext_vector_type(8))) unsigned short us8;
typedef __attribute__((ext_vector_type(4))) unsigned int u32x4;

#define AS1 __attribute__((address_space(1)))
#define AS3 __attribute__((address_space(3)))

__device__ __forceinline__ unsigned short f2bf(float f) {
    unsigned u = __float_as_uint(f);
    u += 0x7fff + ((u >> 16) & 1);   // RNE
    return (unsigned short)(u >> 16);
}

__device__ __forceinline__ unsigned cvtpk_bf16(float lo, float hi) {
    unsigned r;
    asm("v_cvt_pk_bf16_f32 %0, %1, %2" : "=v"(r) : "v"(lo), "v"(hi));
    return r;
}

__device__ __forceinline__ float fast_exp2(float x) {
    float r;
    asm("v_exp_f32 %0, %1" : "=v"(r) : "v"(x));
    return r;
}

// ---------------------------------------------------------------- convert x
__global__ void k_convert_x(const float* __restrict__ x, ushort_t* __restrict__ xb, int n4) {
    int i = blockIdx.x * blockDim.x + threadIdx.x;
    int stride = gridDim.x * blockDim.x;
    for (; i < n4; i += stride) {
        float4 f = reinterpret_cast<const float4*>(x)[i];
        us4 o = { f2bf(f.x), f2bf(f.y), f2bf(f.z), f2bf(f.w) };
        reinterpret_cast<us4*>(xb)[i] = o;
    }
}

// ------------------------------------------------- transpose weights -> bf16 [n][k]
__global__ void k_transpose_w(const float* __restrict__ wq, const float* __restrict__ wk,
                              const float* __restrict__ wv, const float* __restrict__ wo,
                              ushort_t* __restrict__ wqkvt, ushort_t* __restrict__ wot) {
    __shared__ float t[64][65];
    int bx = blockIdx.x;
    int w = bx >> 8;            // 0..3 : WQ WK WV WO
    int ti = bx & 255;
    int k0 = (ti >> 4) * 64, n0 = (ti & 15) * 64;
    const float* src = (w == 0) ? wq : (w == 1) ? wk : (w == 2) ? wv : wo;
    ushort_t* dst = (w < 3) ? (wqkvt + (size_t)w * 1048576) : wot;
    for (int i = threadIdx.x; i < 4096; i += 256) {
        int r = i >> 6, c = i & 63;
        t[c][r] = src[(size_t)(k0 + r) * 1024 + n0 + c];
    }
    __syncthreads();
    for (int i = threadIdx.x; i < 4096; i += 256) {
        int r = i >> 6, c = i & 63;
        dst[(size_t)(n0 + r) * 1024 + k0 + c] = f2bf(t[r][c]);
    }
}

// ---------------------------------------------------------------- QKV GEMM, 256x256 tile, 8-wave phase pipeline
// A = xb[8192][1024] bf16; B = wqkvt[3072 n][1024 k] bf16.
// LDS: 2 bufs x (A 32KB + B 32KB); stored as 16x32-bf16 subtiles (1024B), st_16x32 swizzle:
//   source pre-swizzle cbyte = ((l&3)*16) ^ ((l>>5)<<5); read offset (lr*64+lg*16) ^ ((lr>>3)<<5).
// Phases per K-tile (BK=64): (kk0,mh0) (kk0,mh1) (kk1,mh0) (kk1,mh1), 16 MFMA each.
// Stages for tile kt+2 issued into regions freed by the previous phase's barrier.
// Counted s_waitcnt vmcnt(8) at tile top only; raw barriers with lgkmcnt(0).
__global__ __launch_bounds__(512, 2) void k_gemm_qkv256(
    const ushort_t* __restrict__ A, const ushort_t* __restrict__ Bm,
    ushort_t* __restrict__ qd, ushort_t* __restrict__ kd, ushort_t* __restrict__ vd) {
    __shared__ __attribute__((aligned(16))) ushort_t lds[2 * 32768];   // 128 KiB

    const int tid = threadIdx.x, wid = tid >> 6, lane = tid & 63;
    const int lr = lane & 15, lg = lane >> 4;
    const int wm = wid >> 2, wn = wid & 3;

    int bid = blockIdx.x;                       // 384 = 48 per XCD
    int wg = (bid & 7) * 48 + (bid >> 3);       // bijective XCD swizzle
    const int by = wg / 12, bx = wg % 12;
    const int row0 = by * 256, col0 = bx * 256;

    const int srcrow = lane >> 2;
    const int srccol = (((lane & 3) * 16) ^ ((lane >> 5) << 5)) >> 1;   // ushort units
    const ushort_t* aS = A  + (size_t)(row0 + srcrow) * 1024 + srccol;
    const ushort_t* bS = Bm + (size_t)(col0 + srcrow) * 1024 + srccol;
    const int rdoff = (lr * 64 + lg * 16) ^ ((lr >> 3) << 5);           // bytes

    const int s0 = (wid & 3) + ((wid >> 2) << 3);   // {0..3, 8..11}
    const int s1 = s0 + 4;                          // {4..7, 12..15}

#define STG_A(kt, sr, sc) \
    __builtin_amdgcn_global_load_lds((const AS1 void*)(aS + (size_t)(sr) * 16384 + (kt) * 64 + (sc) * 32), \
        (AS3 void*)((AS3 char*)lds + (((kt) & 1) << 16) + (sr) * 2048 + (sc) * 1024), 16, 0, 0)
#define STG_B(kt, sr, sc) \
    __builtin_amdgcn_global_load_lds((const AS1 void*)(bS + (size_t)(sr) * 16384 + (kt) * 64 + (sc) * 32), \
        (AS3 void*)((AS3 char*)lds + (((kt) & 1) << 16) + 32768 + (sr) * 2048 + (sc) * 1024), 16, 0, 0)
#define ISSUE_P1(kt)  { STG_A(kt, s0, 0); }
#define ISSUE_P2(kt)  { STG_A(kt, s1, 0); STG_B(kt, 2 * wid, 0); STG_B(kt, 2 * wid + 1, 0); }
#define ISSUE_P3(kt)  { STG_A(kt, s0, 1); }
#define ISSUE_TOP(kt) { STG_A(kt, s1, 1); STG_B(kt, 2 * wid, 1); STG_B(kt, 2 * wid + 1, 1); }

    f32x4 acc[8][4] = {};

    // prologue: tile0 fully, tile1 first 5 loads
    ISSUE_P1(0); ISSUE_P2(0); ISSUE_P3(0); ISSUE_TOP(0);
    ISSUE_P1(1); ISSUE_P2(1); ISSUE_P3(1);

#pragma unroll 1
    for (int kt = 0; kt < 16; ++kt) {
        if (kt < 15) {
            ISSUE_TOP(kt + 1);
            asm volatile("s_waitcnt vmcnt(8)" ::: "memory");
        } else {
            asm volatile("s_waitcnt vmcnt(0)" ::: "memory");
        }
        __builtin_amdgcn_s_barrier();

        const char* bufA = (const char*)lds + ((kt & 1) << 16);
        const char* bufB = bufA + 32768;
        bf16x8 av[4], bv[4];

        // ---- phase 0: kk=0, mh=0 (A sr wm*8+0..3 sc0; B sr wn*4+0..3 sc0)
#pragma unroll
        for (int x = 0; x < 4; ++x) {
            av[x] = *reinterpret_cast<const bf16x8*>(bufA + (wm * 8 + x) * 2048 + rdoff);
            bv[x] = *reinterpret_cast<const bf16x8*>(bufB + (wn * 4 + x) * 2048 + rdoff);
        }
        __builtin_amdgcn_s_setprio(1);
#pragma unroll
        for (int mf = 0; mf < 4; ++mf)
#pragma unroll
            for (int nf = 0; nf < 4; ++nf)
                acc[mf][nf] = __builtin_amdgcn_mfma_f32_16x16x32_bf16(av[mf], bv[nf], acc[mf][nf], 0, 0, 0);
        __builtin_amdgcn_s_setprio(0);
        asm volatile("s_waitcnt lgkmcnt(0)" ::: "memory");
        __builtin_amdgcn_s_barrier();

        // ---- phase 1: kk=0, mh=1 (stage A(s0,0) of kt+2 into region read at ph0)
        if (kt < 14) ISSUE_P1(kt + 2);
#pragma unroll
        for (int x = 0; x < 4; ++x)
            av[x] = *reinterpret_cast<const bf16x8*>(bufA + (wm * 8 + 4 + x) * 2048 + rdoff);
        __builtin_amdgcn_s_setprio(1);
#pragma unroll
        for (int mf = 0; mf < 4; ++mf)
#pragma unroll
            for (int nf = 0; nf < 4; ++nf)
                acc[4 + mf][nf] = __builtin_amdgcn_mfma_f32_16x16x32_bf16(av[mf], bv[nf], acc[4 + mf][nf], 0, 0, 0);
        __builtin_amdgcn_s_setprio(0);
        asm volatile("s_waitcnt lgkmcnt(0)" ::: "memory");
        __builtin_amdgcn_s_barrier();

        // ---- phase 2: kk=1, mh=0 (stage A(s1,0)+B(*,0) of kt+2)
        if (kt < 14) ISSUE_P2(kt + 2);
#pragma unroll
        for (int x = 0; x < 4; ++x) {
            av[x] = *reinterpret_cast<const bf16x8*>(bufA + (wm * 8 + x) * 2048 + 1024 + rdoff);
            bv[x] = *reinterpret_cast<const bf16x8*>(bufB + (wn * 4 + x) * 2048 + 1024 + rdoff);
        }
        __builtin_amdgcn_s_setprio(1);
#pragma unroll
        for (int mf = 0; mf < 4; ++mf)
#pragma unroll
            for (int nf = 0; nf < 4; ++nf)
                acc[mf][nf] = __builtin_amdgcn_mfma_f32_16x16x32_bf16(av[mf], bv[nf], acc[mf][nf], 0, 0, 0);
        __builtin_amdgcn_s_setprio(0);
        asm volatile("s_waitcnt lgkmcnt(0)" ::: "memory");
        __builtin_amdgcn_s_barrier();

        // ---- phase 3: kk=1, mh=1 (stage A(s0,1) of kt+2)
        if (kt < 14) ISSUE_P3(kt + 2);
#pragma unroll
        for (int x = 0; x < 4; ++x)
            av[x] = *reinterpret_cast<const bf16x8*>(bufA + (wm * 8 + 4 + x) * 2048 + 1024 + rdoff);
        __builtin_amdgcn_s_setprio(1);
#pragma unroll
        for (int mf = 0; mf < 4; ++mf)
#pragma unroll
            for (int nf = 0; nf < 4; ++nf)
                acc[4 + mf][nf] = __builtin_amdgcn_mfma_f32_16x16x32_bf16(av[mf], bv[nf], acc[4 + mf][nf], 0, 0, 0);
        __builtin_amdgcn_s_setprio(0);
        asm volatile("s_waitcnt lgkmcnt(0)" ::: "memory");
        __builtin_amdgcn_s_barrier();
    }
#undef STG_A
#undef STG_B
#undef ISSUE_P1
#undef ISSUE_P2
#undef ISSUE_P3
#undef ISSUE_TOP

    // ---- epilogue: scatter to [B,H,T,Dh], Q pre-scaled
    const int w = bx >> 2;   // 0:Q 1:K 2:V (uniform per block)
    ushort_t* dst = (w == 0) ? qd : (w == 1) ? kd : vd;
    const float osc = (w == 0) ? 0.18033688f : 1.0f;   // 0.125*log2(e) for Q
#pragma unroll
    for (int mi = 0; mi < 8; ++mi) {
#pragma unroll
        for (int nf = 0; nf < 4; ++nf) {
            int col = col0 + wn * 64 + nf * 16 + lr;
            int c1 = col & 1023;
            int h = c1 >> 6, dh = c1 & 63;
#pragma unroll
            for (int e = 0; e < 4; ++e) {
                int row = row0 + wm * 128 + mi * 16 + lg * 4 + e;
                int b = row >> 11, t = row & 2047;
                dst[(((size_t)(b * 16 + h)) * 2048 + t) * 64 + dh] = f2bf(acc[mi][nf][e] * osc);
            }
        }
    }
}

// ---------------------------------------------------------------- V transpose [bh][t][dh] -> [bh][dh][t]
__global__ __launch_bounds__(256) void k_transpose_v(const ushort_t* __restrict__ vd,
                                                     ushort_t* __restrict__ vt) {
    __shared__ __attribute__((aligned(16))) ushort_t tile[64 * 72];  // col ^= ((t>>3)&7)<<3
    int bid = blockIdx.x;            // 64 bh x 32 ttiles
    int bh = bid >> 5, tt = bid & 31;
    const ushort_t* src = vd + ((size_t)bh * 2048 + tt * 64) * 64;
    ushort_t* dst = vt + (size_t)bh * 2048 * 64 + tt * 64;
#pragma unroll
    for (int r = 0; r < 2; ++r) {
        int i = r * 256 + threadIdx.x;
        int t = i >> 3, c8 = (i & 7) * 8;
        us8 v = *reinterpret_cast<const us8*>(src + (size_t)t * 64 + c8);
        *reinterpret_cast<us8*>(&tile[t * 72 + (c8 ^ ((t >> 3) << 3))]) = v;
    }
    __syncthreads();
#pragma unroll
    for (int r = 0; r < 2; ++r) {
        int i = r * 256 + threadIdx.x;
        int dh = i >> 3, t8 = (i & 7) * 8;
        us8 o;
#pragma unroll
        for (int e = 0; e < 8; ++e)
            o[e] = tile[(t8 + e) * 72 + (dh ^ ((t8 >> 3) << 3))];
        *reinterpret_cast<us8*>(dst + (size_t)dh * 2048 + t8) = o;
    }
}

// ---------------------------------------------------------------- attention
// 512 blocks: 64 bh x 8 pair-index; pass 0 handles q-tile 15-pi (big), pass 1 handles pi
// -> uniform 17 KV-128 iterations per block. 4 waves x 32 q-rows.
// Swapped QK^T (S^T = K x Q) in exp2 domain with NO max tracking (scores bounded);
// ctx^T = V^T x P^T; row-sum via MFMA with A=ones. KV staged 128 keys/barrier,
// double-buffered (64KB), global_load_lds w16 with pre-swizzled source.
__global__ __launch_bounds__(256) void k_attn(
    const ushort_t* __restrict__ q, const ushort_t* __restrict__ k,
    const ushort_t* __restrict__ v, ushort_t* __restrict__ ctx) {
    __shared__ __attribute__((aligned(16))) ushort_t lsK[2 * 8192];  // 2 bufs x [2][64 key][64 dh]
    __shared__ __attribute__((aligned(16))) ushort_t lsV[2 * 8192];  // 2 bufs x [2][64 dh][64 key]

    const int tid = threadIdx.x, wid = tid >> 6, lane = tid & 63;
    const int l31 = lane & 31, hi = lane >> 5;
    const int bid = blockIdx.x;
    const int bh = bid >> 3, pi = bid & 7;
    const size_t base = (size_t)bh * 2048 * 64;
    const ushort_t* qg = q + base;
    const ushort_t* kg = k + base;
    const ushort_t* vtg = v + base;          // [dh][t]
    const int b = bh >> 4, h = bh & 15;

    const int skey = wid * 8 + (lane >> 3);
    const int scb0 = ((lane & 7) * 16) ^ ((skey & 7) << 4);  // swizzled byte-in-row
    const int kx = (l31 & 7) << 4;
    int koffA[4];
#pragma unroll
    for (int s = 0; s < 4; ++s)
        koffA[s] = l31 * 128 + ((s * 32 + hi * 16) ^ kx);

    us8 ow;
#pragma unroll
    for (int e = 0; e < 8; ++e) ow[e] = 0x3F80;              // bf16 1.0
    const bf16x8 onef = __builtin_bit_cast(bf16x8, ow);

#pragma unroll 1
    for (int pass = 0; pass < 2; ++pass) {
        const int qt = pass ? pi : (15 - pi);
        const int q0 = qt * 128;
        const int q0w = q0 + wid * 32;
        const int qrow = q0w + l31;
        const int njt = qt + 1;              // 128-key tiles

        bf16x8 qf[4];
#pragma unroll
        for (int s = 0; s < 4; ++s)
            qf[s] = *reinterpret_cast<const bf16x8*>(qg + (size_t)qrow * 64 + s * 16 + hi * 8);

        const ushort_t* kpr[4];
        const ushort_t* vpr[4];
#pragma unroll
        for (int r = 0; r < 4; ++r) {
            kpr[r] = kg + (size_t)(r * 32 + skey) * 64 + (scb0 >> 1);
            vpr[r] = vtg + (size_t)((r & 1) * 32 + skey) * 2048 + (r >> 1) * 64 + (scb0 >> 1);
        }

        f32x16 acc0 = {}, acc1 = {}, lacc = {};

        __syncthreads();                     // protect LDS from previous pass readers
#pragma unroll
        for (int r = 0; r < 4; ++r) {        // stage tile 0 -> buffer 0
            __builtin_amdgcn_global_load_lds((const AS1 void*)kpr[r],
                (AS3 void*)((AS3 char*)lsK + r * 4096 + wid * 1024), 16, 0, 0);
            __builtin_amdgcn_global_load_lds((const AS1 void*)vpr[r],
                (AS3 void*)((AS3 char*)lsV + r * 4096 + wid * 1024), 16, 0, 0);
        }

        unsigned bo = 0;
        for (int jt = 0; jt < njt; ++jt) {
            __syncthreads();                 // tile jt resident (each wave drained own vmcnt)
            const int j0 = jt << 7;
            if (jt + 1 < njt) {
                const unsigned nb = bo ^ 16384;
#pragma unroll
                for (int r = 0; r < 4; ++r) {
                    kpr[r] += 8192;
                    vpr[r] += 128;
                    __builtin_amdgcn_global_load_lds((const AS1 void*)kpr[r],
                        (AS3 void*)((AS3 char*)lsK + nb + r * 4096 + wid * 1024), 16, 0, 0);
                    __builtin_amdgcn_global_load_lds((const AS1 void*)vpr[r],
                        (AS3 void*)((AS3 char*)lsV + nb + r * 4096 + wid * 1024), 16, 0, 0);
                }
            }

#pragma unroll
            for (int hh = 0; hh < 2; ++hh) {
                const int j0h = j0 + hh * 64;
                if (j0h < q0w + 32) {
                    const char* bK = reinterpret_cast<const char*>(lsK) + bo + hh * 8192;
                    const char* bV = reinterpret_cast<const char*>(lsV) + bo + hh * 8192;

                    // ---- S^T = K x Q
                    f32x16 s0 = {}, s1 = {};
#pragma unroll
                    for (int s = 0; s < 4; ++s) {
                        bf16x8 ka = *reinterpret_cast<const bf16x8*>(bK + koffA[s]);
                        s0 = __builtin_amdgcn_mfma_f32_32x32x16_bf16(ka, qf[s], s0, 0, 0, 0);
                    }
#pragma unroll
                    for (int s = 0; s < 4; ++s) {
                        bf16x8 ka = *reinterpret_cast<const bf16x8*>(bK + 4096 + koffA[s]);
                        s1 = __builtin_amdgcn_mfma_f32_32x32x16_bf16(ka, qf[s], s1, 0, 0, 0);
                    }

                    // ---- P = exp2(S) with causal zeroing (no max tracking: scores bounded)
                    float p0[16], p1[16];
                    if (j0h + 63 > q0w) {
                        const int jh = j0h + 4 * hi;
#pragma unroll
                        for (int r = 0; r < 16; ++r) {
                            const int kl = jh + (r & 3) + 8 * (r >> 2);
                            float e0 = fast_exp2(s0[r]);
                            float e1 = fast_exp2(s1[r]);
                            p0[r] = (kl > qrow) ? 0.f : e0;
                            p1[r] = (kl + 32 > qrow) ? 0.f : e1;
                        }
                    } else {
#pragma unroll
                        for (int r = 0; r < 16; ++r) {
                            p0[r] = fast_exp2(s0[r]);
                            p1[r] = fast_exp2(s1[r]);
                        }
                    }

                    // ---- pack P -> bf16 frags; PV and row-sum via MFMA
#pragma unroll
                    for (int kb = 0; kb < 2; ++kb) {
                        const float* pp = kb ? p1 : p0;
                        unsigned pw[8];
#pragma unroll
                        for (int g = 0; g < 4; ++g) {
                            pw[2 * g]     = cvtpk_bf16(pp[4 * g],     pp[4 * g + 1]);
                            pw[2 * g + 1] = cvtpk_bf16(pp[4 * g + 2], pp[4 * g + 3]);
                        }
#pragma unroll
                        for (int j = 0; j < 2; ++j) {
                            asm("v_permlane32_swap_b32 %0, %1" : "+v"(pw[4 * j]),     "+v"(pw[4 * j + 2]));
                            asm("v_permlane32_swap_b32 %0, %1" : "+v"(pw[4 * j + 1]), "+v"(pw[4 * j + 3]));
                            u32x4 fw = { pw[4 * j], pw[4 * j + 1], pw[4 * j + 2], pw[4 * j + 3] };
                            bf16x8 pf = __builtin_bit_cast(bf16x8, fw);
                            const int jj = kb * 2 + j;
                            {
                                bf16x8 vf = *reinterpret_cast<const bf16x8*>(bV + koffA[jj]);
                                acc0 = __builtin_amdgcn_mfma_f32_32x32x16_bf16(vf, pf, acc0, 0, 0, 0);
                            }
                            {
                                bf16x8 vf = *reinterpret_cast<const bf16x8*>(bV + 4096 + koffA[jj]);
                                acc1 = __builtin_amdgcn_mfma_f32_32x32x16_bf16(vf, pf, acc1, 0, 0, 0);
                            }
                            lacc = __builtin_amdgcn_mfma_f32_32x32x16_bf16(onef, pf, lacc, 0, 0, 0);
                        }
                    }
                }
            }
            bo ^= 16384;
        }

        // ---- epilogue: ctx[b][t=qrow][h*64 + dh]
        float inv = 1.0f / lacc[0];
        size_t orow = ((size_t)(b * 2048 + qrow)) * 1024 + h * 64;
#pragma unroll
        for (int g = 0; g < 4; ++g) {
            us4 o0 = { f2bf(acc0[4 * g] * inv),     f2bf(acc0[4 * g + 1] * inv),
                       f2bf(acc0[4 * g + 2] * inv), f2bf(acc0[4 * g + 3] * inv) };
            *reinterpret_cast<us4*>(&ctx[orow + 8 * g + 4 * hi]) = o0;
            us4 o1 = { f2bf(acc1[4 * g] * inv),     f2bf(acc1[4 * g + 1] * inv),
                       f2bf(acc1[4 * g + 2] * inv), f2bf(acc1[4 * g + 3] * inv) };
            *reinterpret_cast<us4*>(&ctx[orow + 32 + 8 * g + 4 * hi]) = o1;
        }
    }
}

// ---------------------------------------------------------------- out GEMM (+bias, f32 out)
__global__ __launch_bounds__(256) void k_gemm_out(
    const ushort_t* __restrict__ cb, const ushort_t* __restrict__ wot,
    const float* __restrict__ bO, float* __restrict__ out) {
    __shared__ ushort_t lA[128 * 32];
    __shared__ ushort_t lB[128 * 32];
    const int tid = threadIdx.x, wid = tid >> 6, lane = tid & 63;
    const int lr = lane & 15, lg = lane >> 4;
    const int wm = wid >> 1, wn = wid & 1;
    const int bx = blockIdx.x;
    const int by = blockIdx.y;
    const int row0 = by * 128, col0 = bx * 128;
    const int crow = lane >> 2;
    const int coff = (lane & 3) * 8;

    f32x4 acc[4][4] = {};

    for (int k0 = 0; k0 < 1024; k0 += 32) {
        for (int c = wid; c < 8; c += 4) {
            const ushort_t* ga = cb + (size_t)(row0 + c * 16 + crow) * 1024 + k0 + coff;
            __builtin_amdgcn_global_load_lds((const AS1 void*)ga, (AS3 void*)(lA + c * 512), 16, 0, 0);
            const ushort_t* gb = wot + (size_t)(col0 + c * 16 + crow) * 1024 + k0 + coff;
            __builtin_amdgcn_global_load_lds((const AS1 void*)gb, (AS3 void*)(lB + c * 512), 16, 0, 0);
        }
        __syncthreads();
        bf16x8 af[4], bfr[4];
#pragma unroll
        for (int i = 0; i < 4; ++i) {
            af[i]  = *reinterpret_cast<const bf16x8*>(lA + (wm * 64 + i * 16 + lr) * 32 + lg * 8);
            bfr[i] = *reinterpret_cast<const bf16x8*>(lB + (wn * 64 + i * 16 + lr) * 32 + lg * 8);
        }
#pragma unroll
        for (int mi = 0; mi < 4; ++mi)
#pragma unroll
            for (int ni = 0; ni < 4; ++ni)
                acc[mi][ni] = __builtin_amdgcn_mfma_f32_16x16x32_bf16(af[mi], bfr[ni], acc[mi][ni], 0, 0, 0);
        __syncthreads();
    }

#pragma unroll
    for (int mi = 0; mi < 4; ++mi) {
#pragma unroll
        for (int ni = 0; ni < 4; ++ni) {
            int col = col0 + wn * 64 + ni * 16 + lr;
            float bias = bO[col];
#pragma unroll
            for (int e = 0; e < 4; ++e) {
                int row = row0 + wm * 64 + mi * 16 + lg * 4 + e;
                out[(size_t)row * 1024 + col] = acc[mi][ni][e] + bias;
            }
        }
    }
}

// ---------------------------------------------------------------- launch
extern "C" void kernel_launch(void* const* d_in, const int* in_sizes, int n_in,
                              void* d_out, int out_size, void* d_ws, size_t ws_size,
                              hipStream_t stream) {
    const float* x  = (const float*)d_in[0];
    const float* wq = (const float*)d_in[1];
    const float* wk = (const float*)d_in[2];
    const float* wv = (const float*)d_in[3];
    const float* wo = (const float*)d_in[4];
    const float* bo = (const float*)d_in[5];
    float* out = (float*)d_out;

    char* ws = (char*)d_ws;
    ushort_t* xb    = (ushort_t*)(ws);                 // 16 MB   x bf16 [8192][1024]; reused as V^T after gemm
    ushort_t* wqkvt = (ushort_t*)(ws + 16777216);      // 6 MB    [3][1024 n][1024 k] = [3072][1024]
    ushort_t* wot   = (ushort_t*)(ws + 23068672);      // 2 MB    [1024 n][1024 k]
    ushort_t* qd    = (ushort_t*)(ws + 25165824);      // 16 MB   [B,H,T,Dh] (pre-scaled)
    ushort_t* kd    = (ushort_t*)(ws + 41943040);      // 16 MB   [B,H,T,Dh]
    ushort_t* vd    = (ushort_t*)(ws + 58720256);      // 16 MB   [B,H,T,Dh]
    ushort_t* cd    = (ushort_t*)(ws + 75497472);      // 16 MB   ctx bf16 [8192][1024]
    ushort_t* vt    = xb;                              // V^T [B,H,Dh,T] (xb dead after gemm_qkv)

    k_convert_x<<<2048, 256, 0, stream>>>(x, xb, 8192 * 1024 / 4);
    k_transpose_w<<<1024, 256, 0, stream>>>(wq, wk, wv, wo, wqkvt, wot);
    k_gemm_qkv256<<<384, 512, 0, stream>>>(xb, wqkvt, qd, kd, vd);
    k_transpose_v<<<2048, 256, 0, stream>>>(vd, vt);
    k_attn<<<512, 256, 0, stream>>>(qd, kd, vt, cd);
    k_gemm_out<<<dim3(8, 64), 256, 0, stream>>>(cd, wot, bo, out);
}

// Round 6
// 168.673 us; speedup vs baseline: 2.4501x; 1.0379x over previous
//
#include <hip/hip_runtime.h>

typedef unsigned short ushort_t;
typedef __attribute__((ext_vector_type(8))) __bf16 bf16x8;
typedef __attribute__((ext_vector_type(4))) float f32x4;
typedef __attribute__((ext_vector_type(16))) float f32x16;
typedef __attribute__((ext_vector_type(4))) unsigned short us4;
typedef __attribute__((ext_vector_type(8))) unsigned short us8;
typedef __attribute__((ext_vector_type(4))) unsigned int u32x4;

#define AS1 __attribute__((address_space(1)))
#define AS3 __attribute__((address_space(3)))

__device__ __forceinline__ unsigned short f2bf(float f) {
    unsigned u = __float_as_uint(f);
    u += 0x7fff + ((u >> 16) & 1);   // RNE
    return (unsigned short)(u >> 16);
}

__device__ __forceinline__ unsigned cvtpk_bf16(float lo, float hi) {
    unsigned r;
    asm("v_cvt_pk_bf16_f32 %0, %1, %2" : "=v"(r) : "v"(lo), "v"(hi));
    return r;
}

__device__ __forceinline__ float fast_exp2(float x) {
    float r;
    asm("v_exp_f32 %0, %1" : "=v"(r) : "v"(x));
    return r;
}

// ---------------------------------------------------------------- convert x
__global__ void k_convert_x(const float* __restrict__ x, ushort_t* __restrict__ xb, int n4) {
    int i = blockIdx.x * blockDim.x + threadIdx.x;
    int stride = gridDim.x * blockDim.x;
    for (; i < n4; i += stride) {
        float4 f = reinterpret_cast<const float4*>(x)[i];
        us4 o = { f2bf(f.x), f2bf(f.y), f2bf(f.z), f2bf(f.w) };
        reinterpret_cast<us4*>(xb)[i] = o;
    }
}

// ------------------------------------------------- transpose weights -> bf16 [n][k]
__global__ void k_transpose_w(const float* __restrict__ wq, const float* __restrict__ wk,
                              const float* __restrict__ wv, const float* __restrict__ wo,
                              ushort_t* __restrict__ wqkvt, ushort_t* __restrict__ wot) {
    __shared__ float t[64][65];
    int bx = blockIdx.x;
    int w = bx >> 8;            // 0..3 : WQ WK WV WO
    int ti = bx & 255;
    int k0 = (ti >> 4) * 64, n0 = (ti & 15) * 64;
    const float* src = (w == 0) ? wq : (w == 1) ? wk : (w == 2) ? wv : wo;
    ushort_t* dst = (w < 3) ? (wqkvt + (size_t)w * 1048576) : wot;
    for (int i = threadIdx.x; i < 4096; i += 256) {
        int r = i >> 6, c = i & 63;
        t[c][r] = src[(size_t)(k0 + r) * 1024 + n0 + c];
    }
    __syncthreads();
    for (int i = threadIdx.x; i < 4096; i += 256) {
        int r = i >> 6, c = i & 63;
        dst[(size_t)(n0 + r) * 1024 + k0 + c] = f2bf(t[r][c]);
    }
}

// ---------------------------------------------------------------- QKV GEMM, 256x192 tile, pipelined phases
// A = xb[8192][1024] bf16; B = wqkvt[3072 n][1024 k] bf16. Grid 32x16 = 512 blocks = 2 exact rounds.
// LDS 112 KiB: 2 bufs x (A 32K: 16sr x 2sc x 1024B subtiles; B 24K: 12sr x 2sc).
// Subtile 16rows x 32cols bf16; source pre-swizzle ((l&3)*16)^((l>>5)<<5), read
// (lr*64+lg*16)^((lr>>3)<<5) -- proven 0-conflict (round 5).
// Per tile (BK=64): 4 phases x 12 MFMA; ds_reads for phase p+1 issued in phase p's slot;
// stage groups for kt+2 delayed so each is barrier-separated from that region's last read.
// vmcnt(5) counted once per tile; 4 barriers/tile.
__global__ __launch_bounds__(512, 2) void k_gemm_qkv256(
    const ushort_t* __restrict__ A, const ushort_t* __restrict__ Bm,
    ushort_t* __restrict__ qd, ushort_t* __restrict__ kd, ushort_t* __restrict__ vd) {
    __shared__ __attribute__((aligned(16))) ushort_t lds[2 * 28672];   // 112 KiB

    const int tid = threadIdx.x, wid = tid >> 6, lane = tid & 63;
    const int lr = lane & 15, lg = lane >> 4;
    const int wm = wid >> 2, wn = wid & 3;

    int bid = blockIdx.x;                       // 512 = 64 per XCD
    int wg = (bid & 7) * 64 + (bid >> 3);       // bijective XCD swizzle
    const int by = wg >> 4, bx = wg & 15;
    const int row0 = by * 256, col0 = bx * 192;

    const int srcrow = lane >> 2;
    const int srccol = (((lane & 3) * 16) ^ ((lane >> 5) << 5)) >> 1;   // ushort units
    const ushort_t* aS = A  + (size_t)(row0 + srcrow) * 1024 + srccol;
    const ushort_t* bS = Bm + (size_t)(col0 + srcrow) * 1024 + srccol;
    const int rdoff = (lr * 64 + lg * 16) ^ ((lr >> 3) << 5);           // bytes

    const int s0 = (wid & 3) + ((wid >> 2) << 3);   // A sr set {0..3, 8..11}
    const int s1 = s0 + 4;                          // A sr set {4..7, 12..15}
    const int bmix_sr = 8 + (wid & 3);              // B sr 8..11
    const int bmix_sc = wid >> 2;

#define STG_A(kt, sr, sc) \
    __builtin_amdgcn_global_load_lds((const AS1 void*)(aS + (size_t)(sr) * 16384 + (kt) * 64 + (sc) * 32), \
        (AS3 void*)((AS3 char*)lds + ((kt) & 1) * 57344 + (sr) * 2048 + (sc) * 1024), 16, 0, 0)
#define STG_B(kt, sr, sc) \
    __builtin_amdgcn_global_load_lds((const AS1 void*)(bS + (size_t)(sr) * 16384 + (kt) * 64 + (sc) * 32), \
        (AS3 void*)((AS3 char*)lds + ((kt) & 1) * 57344 + 32768 + (sr) * 2048 + (sc) * 1024), 16, 0, 0)
#define GRP1(kt)  { STG_A(kt, s0, 0); STG_B(kt, wid, 0); }   // 2 loads
#define GRP2(kt)  { STG_A(kt, s1, 0); }                      // 1 load
#define GRP3(kt)  { STG_A(kt, s0, 1); STG_B(kt, wid, 1); }   // 2 loads
#define GTOP(kt)  { STG_A(kt, s1, 1); STG_B(kt, bmix_sr, bmix_sc); }  // 2 loads

    f32x4 acc[8][3] = {};

    // prologue: tile0 complete (7), tile1 in-loop groups (5)
    GRP1(0); GRP2(0); GRP3(0); GTOP(0);
    GRP1(1); GRP2(1); GRP3(1);

#pragma unroll 1
    for (int kt = 0; kt < 16; ++kt) {
        if (kt < 15) asm volatile("s_waitcnt vmcnt(5)" ::: "memory");
        else         asm volatile("s_waitcnt vmcnt(0)" ::: "memory");
        __builtin_amdgcn_s_barrier();                 // buffer kt valid for all waves
        if (kt < 15) GTOP(kt + 1);

        const char* bufA = (const char*)lds + (kt & 1) * 57344;
        const char* bufB = bufA + 32768;

        bf16x8 av0[4], av1[4], bv0[3], bv1[3];
        // reads for phase 0 (sc0, mh0) + B sc0
#pragma unroll
        for (int x = 0; x < 4; ++x)
            av0[x] = *reinterpret_cast<const bf16x8*>(bufA + (wm * 8 + x) * 2048 + rdoff);
#pragma unroll
        for (int x = 0; x < 3; ++x)
            bv0[x] = *reinterpret_cast<const bf16x8*>(bufB + (wn * 3 + x) * 2048 + rdoff);

        // ---- phase 0: MFMA(av0,bv0 -> acc[0..3]); reads for phase 1 (sc0, mh1)
#pragma unroll
        for (int x = 0; x < 4; ++x)
            av1[x] = *reinterpret_cast<const bf16x8*>(bufA + (wm * 8 + 4 + x) * 2048 + rdoff);
        __builtin_amdgcn_s_setprio(1);
#pragma unroll
        for (int mf = 0; mf < 4; ++mf)
#pragma unroll
            for (int nf = 0; nf < 3; ++nf)
                acc[mf][nf] = __builtin_amdgcn_mfma_f32_16x16x32_bf16(av0[mf], bv0[nf], acc[mf][nf], 0, 0, 0);
        __builtin_amdgcn_s_setprio(0);
        __builtin_amdgcn_s_barrier();

        // ---- phase 1: MFMA(av1,bv0 -> acc[4..7]); reads for phase 2 (sc1, mh0 + B sc1); stage GRP1(kt+2)
#pragma unroll
        for (int x = 0; x < 4; ++x)
            av0[x] = *reinterpret_cast<const bf16x8*>(bufA + (wm * 8 + x) * 2048 + 1024 + rdoff);
#pragma unroll
        for (int x = 0; x < 3; ++x)
            bv1[x] = *reinterpret_cast<const bf16x8*>(bufB + (wn * 3 + x) * 2048 + 1024 + rdoff);
        __builtin_amdgcn_s_setprio(1);
#pragma unroll
        for (int mf = 0; mf < 4; ++mf)
#pragma unroll
            for (int nf = 0; nf < 3; ++nf)
                acc[4 + mf][nf] = __builtin_amdgcn_mfma_f32_16x16x32_bf16(av1[mf], bv0[nf], acc[4 + mf][nf], 0, 0, 0);
        __builtin_amdgcn_s_setprio(0);
        if (kt < 14) GRP1(kt + 2);
        __builtin_amdgcn_s_barrier();

        // ---- phase 2: MFMA(av0,bv1 -> acc[0..3]); reads for phase 3 (sc1, mh1); stage GRP2(kt+2)
#pragma unroll
        for (int x = 0; x < 4; ++x)
            av1[x] = *reinterpret_cast<const bf16x8*>(bufA + (wm * 8 + 4 + x) * 2048 + 1024 + rdoff);
        __builtin_amdgcn_s_setprio(1);
#pragma unroll
        for (int mf = 0; mf < 4; ++mf)
#pragma unroll
            for (int nf = 0; nf < 3; ++nf)
                acc[mf][nf] = __builtin_amdgcn_mfma_f32_16x16x32_bf16(av0[mf], bv1[nf], acc[mf][nf], 0, 0, 0);
        __builtin_amdgcn_s_setprio(0);
        if (kt < 14) GRP2(kt + 2);
        __builtin_amdgcn_s_barrier();

        // ---- phase 3: MFMA(av1,bv1 -> acc[4..7]); stage GRP3(kt+2); no barrier (top BAR follows)
        __builtin_amdgcn_s_setprio(1);
#pragma unroll
        for (int mf = 0; mf < 4; ++mf)
#pragma unroll
            for (int nf = 0; nf < 3; ++nf)
                acc[4 + mf][nf] = __builtin_amdgcn_mfma_f32_16x16x32_bf16(av1[mf], bv1[nf], acc[4 + mf][nf], 0, 0, 0);
        __builtin_amdgcn_s_setprio(0);
        if (kt < 14) GRP3(kt + 2);
    }
#undef STG_A
#undef STG_B
#undef GRP1
#undef GRP2
#undef GRP3
#undef GTOP

    // ---- epilogue: scatter to [B,H,T,Dh]; per-fragment Q/K/V select (tiles straddle)
#pragma unroll
    for (int mi = 0; mi < 8; ++mi) {
#pragma unroll
        for (int nf = 0; nf < 3; ++nf) {
            int col = col0 + wn * 48 + nf * 16 + lr;
            int w = col >> 10;
            int c1 = col & 1023;
            int h = c1 >> 6, dh = c1 & 63;
            ushort_t* dst = (w == 0) ? qd : (w == 1) ? kd : vd;
            const float osc = (w == 0) ? 0.18033688f : 1.0f;   // 0.125*log2(e) for Q
#pragma unroll
            for (int e = 0; e < 4; ++e) {
                int row = row0 + wm * 128 + mi * 16 + lg * 4 + e;
                int b = row >> 11, t = row & 2047;
                dst[(((size_t)(b * 16 + h)) * 2048 + t) * 64 + dh] = f2bf(acc[mi][nf][e] * osc);
            }
        }
    }
}

// ---------------------------------------------------------------- V transpose [bh][t][dh] -> [bh][dh][t]
__global__ __launch_bounds__(256) void k_transpose_v(const ushort_t* __restrict__ vd,
                                                     ushort_t* __restrict__ vt) {
    __shared__ __attribute__((aligned(16))) ushort_t tile[64 * 72];  // col ^= ((t>>3)&7)<<3
    int bid = blockIdx.x;            // 64 bh x 32 ttiles
    int bh = bid >> 5, tt = bid & 31;
    const ushort_t* src = vd + ((size_t)bh * 2048 + tt * 64) * 64;
    ushort_t* dst = vt + (size_t)bh * 2048 * 64 + tt * 64;
#pragma unroll
    for (int r = 0; r < 2; ++r) {
        int i = r * 256 + threadIdx.x;
        int t = i >> 3, c8 = (i & 7) * 8;
        us8 v = *reinterpret_cast<const us8*>(src + (size_t)t * 64 + c8);
        *reinterpret_cast<us8*>(&tile[t * 72 + (c8 ^ ((t >> 3) << 3))]) = v;
    }
    __syncthreads();
#pragma unroll
    for (int r = 0; r < 2; ++r) {
        int i = r * 256 + threadIdx.x;
        int dh = i >> 3, t8 = (i & 7) * 8;
        us8 o;
#pragma unroll
        for (int e = 0; e < 8; ++e)
            o[e] = tile[(t8 + e) * 72 + (dh ^ ((t8 >> 3) << 3))];
        *reinterpret_cast<us8*>(dst + (size_t)dh * 2048 + t8) = o;
    }
}

// ---------------------------------------------------------------- attention
// 512 blocks: 64 bh x 8 pair-index; pass 0 handles q-tile 15-pi (big), pass 1 handles pi
// -> uniform 17 KV-128 iterations per block. 4 waves x 32 q-rows.
// Swapped QK^T (S^T = K x Q) in exp2 domain with NO max tracking (scores bounded);
// ctx^T = V^T x P^T; row-sum via MFMA with A=ones. KV staged 128 keys/barrier,
// double-buffered (64KB), global_load_lds w16 with pre-swizzled source.
__global__ __launch_bounds__(256) void k_attn(
    const ushort_t* __restrict__ q, const ushort_t* __restrict__ k,
    const ushort_t* __restrict__ v, ushort_t* __restrict__ ctx) {
    __shared__ __attribute__((aligned(16))) ushort_t lsK[2 * 8192];  // 2 bufs x [2][64 key][64 dh]
    __shared__ __attribute__((aligned(16))) ushort_t lsV[2 * 8192];  // 2 bufs x [2][64 dh][64 key]

    const int tid = threadIdx.x, wid = tid >> 6, lane = tid & 63;
    const int l31 = lane & 31, hi = lane >> 5;
    const int bid = blockIdx.x;
    const int bh = bid >> 3, pi = bid & 7;
    const size_t base = (size_t)bh * 2048 * 64;
    const ushort_t* qg = q + base;
    const ushort_t* kg = k + base;
    const ushort_t* vtg = v + base;          // [dh][t]
    const int b = bh >> 4, h = bh & 15;

    const int skey = wid * 8 + (lane >> 3);
    const int scb0 = ((lane & 7) * 16) ^ ((skey & 7) << 4);  // swizzled byte-in-row
    const int kx = (l31 & 7) << 4;
    int koffA[4];
#pragma unroll
    for (int s = 0; s < 4; ++s)
        koffA[s] = l31 * 128 + ((s * 32 + hi * 16) ^ kx);

    us8 ow;
#pragma unroll
    for (int e = 0; e < 8; ++e) ow[e] = 0x3F80;              // bf16 1.0
    const bf16x8 onef = __builtin_bit_cast(bf16x8, ow);

#pragma unroll 1
    for (int pass = 0; pass < 2; ++pass) {
        const int qt = pass ? pi : (15 - pi);
        const int q0 = qt * 128;
        const int q0w = q0 + wid * 32;
        const int qrow = q0w + l31;
        const int njt = qt + 1;              // 128-key tiles

        bf16x8 qf[4];
#pragma unroll
        for (int s = 0; s < 4; ++s)
            qf[s] = *reinterpret_cast<const bf16x8*>(qg + (size_t)qrow * 64 + s * 16 + hi * 8);

        const ushort_t* kpr[4];
        const ushort_t* vpr[4];
#pragma unroll
        for (int r = 0; r < 4; ++r) {
            kpr[r] = kg + (size_t)(r * 32 + skey) * 64 + (scb0 >> 1);
            vpr[r] = vtg + (size_t)((r & 1) * 32 + skey) * 2048 + (r >> 1) * 64 + (scb0 >> 1);
        }

        f32x16 acc0 = {}, acc1 = {}, lacc = {};

        __syncthreads();                     // protect LDS from previous pass readers
#pragma unroll
        for (int r = 0; r < 4; ++r) {        // stage tile 0 -> buffer 0
            __builtin_amdgcn_global_load_lds((const AS1 void*)kpr[r],
                (AS3 void*)((AS3 char*)lsK + r * 4096 + wid * 1024), 16, 0, 0);
            __builtin_amdgcn_global_load_lds((const AS1 void*)vpr[r],
                (AS3 void*)((AS3 char*)lsV + r * 4096 + wid * 1024), 16, 0, 0);
        }

        unsigned bo = 0;
        for (int jt = 0; jt < njt; ++jt) {
            __syncthreads();                 // tile jt resident (each wave drained own vmcnt)
            const int j0 = jt << 7;
            if (jt + 1 < njt) {
                const unsigned nb = bo ^ 16384;
#pragma unroll
                for (int r = 0; r < 4; ++r) {
                    kpr[r] += 8192;
                    vpr[r] += 128;
                    __builtin_amdgcn_global_load_lds((const AS1 void*)kpr[r],
                        (AS3 void*)((AS3 char*)lsK + nb + r * 4096 + wid * 1024), 16, 0, 0);
                    __builtin_amdgcn_global_load_lds((const AS1 void*)vpr[r],
                        (AS3 void*)((AS3 char*)lsV + nb + r * 4096 + wid * 1024), 16, 0, 0);
                }
            }

#pragma unroll
            for (int hh = 0; hh < 2; ++hh) {
                const int j0h = j0 + hh * 64;
                if (j0h < q0w + 32) {
                    const char* bK = reinterpret_cast<const char*>(lsK) + bo + hh * 8192;
                    const char* bV = reinterpret_cast<const char*>(lsV) + bo + hh * 8192;

                    // ---- S^T = K x Q
                    f32x16 s0 = {}, s1 = {};
#pragma unroll
                    for (int s = 0; s < 4; ++s) {
                        bf16x8 ka = *reinterpret_cast<const bf16x8*>(bK + koffA[s]);
                        s0 = __builtin_amdgcn_mfma_f32_32x32x16_bf16(ka, qf[s], s0, 0, 0, 0);
                    }
#pragma unroll
                    for (int s = 0; s < 4; ++s) {
                        bf16x8 ka = *reinterpret_cast<const bf16x8*>(bK + 4096 + koffA[s]);
                        s1 = __builtin_amdgcn_mfma_f32_32x32x16_bf16(ka, qf[s], s1, 0, 0, 0);
                    }

                    // ---- P = exp2(S) with causal zeroing (no max tracking: scores bounded)
                    float p0[16], p1[16];
                    if (j0h + 63 > q0w) {
                        const int jh = j0h + 4 * hi;
#pragma unroll
                        for (int r = 0; r < 16; ++r) {
                            const int kl = jh + (r & 3) + 8 * (r >> 2);
                            float e0 = fast_exp2(s0[r]);
                            float e1 = fast_exp2(s1[r]);
                            p0[r] = (kl > qrow) ? 0.f : e0;
                            p1[r] = (kl + 32 > qrow) ? 0.f : e1;
                        }
                    } else {
#pragma unroll
                        for (int r = 0; r < 16; ++r) {
                            p0[r] = fast_exp2(s0[r]);
                            p1[r] = fast_exp2(s1[r]);
                        }
                    }

                    // ---- pack P -> bf16 frags; PV and row-sum via MFMA
#pragma unroll
                    for (int kb = 0; kb < 2; ++kb) {
                        const float* pp = kb ? p1 : p0;
                        unsigned pw[8];
#pragma unroll
                        for (int g = 0; g < 4; ++g) {
                            pw[2 * g]     = cvtpk_bf16(pp[4 * g],     pp[4 * g + 1]);
                            pw[2 * g + 1] = cvtpk_bf16(pp[4 * g + 2], pp[4 * g + 3]);
                        }
#pragma unroll
                        for (int j = 0; j < 2; ++j) {
                            asm("v_permlane32_swap_b32 %0, %1" : "+v"(pw[4 * j]),     "+v"(pw[4 * j + 2]));
                            asm("v_permlane32_swap_b32 %0, %1" : "+v"(pw[4 * j + 1]), "+v"(pw[4 * j + 3]));
                            u32x4 fw = { pw[4 * j], pw[4 * j + 1], pw[4 * j + 2], pw[4 * j + 3] };
                            bf16x8 pf = __builtin_bit_cast(bf16x8, fw);
                            const int jj = kb * 2 + j;
                            {
                                bf16x8 vf = *reinterpret_cast<const bf16x8*>(bV + koffA[jj]);
                                acc0 = __builtin_amdgcn_mfma_f32_32x32x16_bf16(vf, pf, acc0, 0, 0, 0);
                            }
                            {
                                bf16x8 vf = *reinterpret_cast<const bf16x8*>(bV + 4096 + koffA[jj]);
                                acc1 = __builtin_amdgcn_mfma_f32_32x32x16_bf16(vf, pf, acc1, 0, 0, 0);
                            }
                            lacc = __builtin_amdgcn_mfma_f32_32x32x16_bf16(onef, pf, lacc, 0, 0, 0);
                        }
                    }
                }
            }
            bo ^= 16384;
        }

        // ---- epilogue: ctx[b][t=qrow][h*64 + dh]
        float inv = 1.0f / lacc[0];
        size_t orow = ((size_t)(b * 2048 + qrow)) * 1024 + h * 64;
#pragma unroll
        for (int g = 0; g < 4; ++g) {
            us4 o0 = { f2bf(acc0[4 * g] * inv),     f2bf(acc0[4 * g + 1] * inv),
                       f2bf(acc0[4 * g + 2] * inv), f2bf(acc0[4 * g + 3] * inv) };
            *reinterpret_cast<us4*>(&ctx[orow + 8 * g + 4 * hi]) = o0;
            us4 o1 = { f2bf(acc1[4 * g] * inv),     f2bf(acc1[4 * g + 1] * inv),
                       f2bf(acc1[4 * g + 2] * inv), f2bf(acc1[4 * g + 3] * inv) };
            *reinterpret_cast<us4*>(&ctx[orow + 32 + 8 * g + 4 * hi]) = o1;
        }
    }
}

// ---------------------------------------------------------------- out GEMM (+bias, f32 out)
__global__ __launch_bounds__(256) void k_gemm_out(
    const ushort_t* __restrict__ cb, const ushort_t* __restrict__ wot,
    const float* __restrict__ bO, float* __restrict__ out) {
    __shared__ ushort_t lA[128 * 32];
    __shared__ ushort_t lB[128 * 32];
    const int tid = threadIdx.x, wid = tid >> 6, lane = tid & 63;
    const int lr = lane & 15, lg = lane >> 4;
    const int wm = wid >> 1, wn = wid & 1;
    const int bx = blockIdx.x;
    const int by = blockIdx.y;
    const int row0 = by * 128, col0 = bx * 128;
    const int crow = lane >> 2;
    const int coff = (lane & 3) * 8;

    f32x4 acc[4][4] = {};

    for (int k0 = 0; k0 < 1024; k0 += 32) {
        for (int c = wid; c < 8; c += 4) {
            const ushort_t* ga = cb + (size_t)(row0 + c * 16 + crow) * 1024 + k0 + coff;
            __builtin_amdgcn_global_load_lds((const AS1 void*)ga, (AS3 void*)(lA + c * 512), 16, 0, 0);
            const ushort_t* gb = wot + (size_t)(col0 + c * 16 + crow) * 1024 + k0 + coff;
            __builtin_amdgcn_global_load_lds((const AS1 void*)gb, (AS3 void*)(lB + c * 512), 16, 0, 0);
        }
        __syncthreads();
        bf16x8 af[4], bfr[4];
#pragma unroll
        for (int i = 0; i < 4; ++i) {
            af[i]  = *reinterpret_cast<const bf16x8*>(lA + (wm * 64 + i * 16 + lr) * 32 + lg * 8);
            bfr[i] = *reinterpret_cast<const bf16x8*>(lB + (wn * 64 + i * 16 + lr) * 32 + lg * 8);
        }
#pragma unroll
        for (int mi = 0; mi < 4; ++mi)
#pragma unroll
            for (int ni = 0; ni < 4; ++ni)
                acc[mi][ni] = __builtin_amdgcn_mfma_f32_16x16x32_bf16(af[mi], bfr[ni], acc[mi][ni], 0, 0, 0);
        __syncthreads();
    }

#pragma unroll
    for (int mi = 0; mi < 4; ++mi) {
#pragma unroll
        for (int ni = 0; ni < 4; ++ni) {
            int col = col0 + wn * 64 + ni * 16 + lr;
            float bias = bO[col];
#pragma unroll
            for (int e = 0; e < 4; ++e) {
                int row = row0 + wm * 64 + mi * 16 + lg * 4 + e;
                out[(size_t)row * 1024 + col] = acc[mi][ni][e] + bias;
            }
        }
    }
}

// ---------------------------------------------------------------- launch
extern "C" void kernel_launch(void* const* d_in, const int* in_sizes, int n_in,
                              void* d_out, int out_size, void* d_ws, size_t ws_size,
                              hipStream_t stream) {
    const float* x  = (const float*)d_in[0];
    const float* wq = (const float*)d_in[1];
    const float* wk = (const float*)d_in[2];
    const float* wv = (const float*)d_in[3];
    const float* wo = (const float*)d_in[4];
    const float* bo = (const float*)d_in[5];
    float* out = (float*)d_out;

    char* ws = (char*)d_ws;
    ushort_t* xb    = (ushort_t*)(ws);                 // 16 MB   x bf16 [8192][1024]; reused as V^T after gemm
    ushort_t* wqkvt = (ushort_t*)(ws + 16777216);      // 6 MB    [3][1024 n][1024 k] = [3072][1024]
    ushort_t* wot   = (ushort_t*)(ws + 23068672);      // 2 MB    [1024 n][1024 k]
    ushort_t* qd    = (ushort_t*)(ws + 25165824);      // 16 MB   [B,H,T,Dh] (pre-scaled)
    ushort_t* kd    = (ushort_t*)(ws + 41943040);      // 16 MB   [B,H,T,Dh]
    ushort_t* vd    = (ushort_t*)(ws + 58720256);      // 16 MB   [B,H,T,Dh]
    ushort_t* cd    = (ushort_t*)(ws + 75497472);      // 16 MB   ctx bf16 [8192][1024]
    ushort_t* vt    = xb;                              // V^T [B,H,Dh,T] (xb dead after gemm_qkv)

    k_convert_x<<<2048, 256, 0, stream>>>(x, xb, 8192 * 1024 / 4);
    k_transpose_w<<<1024, 256, 0, stream>>>(wq, wk, wv, wo, wqkvt, wot);
    k_gemm_qkv256<<<512, 512, 0, stream>>>(xb, wqkvt, qd, kd, vd);
    k_transpose_v<<<2048, 256, 0, stream>>>(vd, vt);
    k_attn<<<512, 256, 0, stream>>>(qd, kd, vt, cd);
    k_gemm_out<<<dim3(8, 64), 256, 0, stream>>>(cd, wot, bo, out);
}

// Round 7
// 156.768 us; speedup vs baseline: 2.6361x; 1.0759x over previous
//
#include <hip/hip_runtime.h>

typedef unsigned short ushort_t;
typedef __attribute__((ext_vector_type(8))) __bf16 bf16x8;
typedef __attribute__((ext_vector_type(4))) float f32x4;
typedef __attribute__((ext_vector_type(16))) float f32x16;
typedef __attribute__((ext_vector_type(4))) unsigned short us4;
typedef __attribute__((ext_vector_type(8))) unsigned short us8;
typedef __attribute__((ext_vector_type(4))) unsigned int u32x4;

#define AS1 __attribute__((address_space(1)))
#define AS3 __attribute__((address_space(3)))

__device__ __forceinline__ unsigned short f2bf(float f) {
    unsigned u = __float_as_uint(f);
    u += 0x7fff + ((u >> 16) & 1);   // RNE
    return (unsigned short)(u >> 16);
}

__device__ __forceinline__ unsigned cvtpk_bf16(float lo, float hi) {
    unsigned r;
    asm("v_cvt_pk_bf16_f32 %0, %1, %2" : "=v"(r) : "v"(lo), "v"(hi));
    return r;
}

__device__ __forceinline__ float fast_exp2(float x) {
    float r;
    asm("v_exp_f32 %0, %1" : "=v"(r) : "v"(x));
    return r;
}

// ---------------------------------------------------------------- convert x
__global__ void k_convert_x(const float* __restrict__ x, ushort_t* __restrict__ xb, int n4) {
    int i = blockIdx.x * blockDim.x + threadIdx.x;
    int stride = gridDim.x * blockDim.x;
    for (; i < n4; i += stride) {
        float4 f = reinterpret_cast<const float4*>(x)[i];
        us4 o = { f2bf(f.x), f2bf(f.y), f2bf(f.z), f2bf(f.w) };
        reinterpret_cast<us4*>(xb)[i] = o;
    }
}

// ------------------------------------------------- transpose weights -> bf16 [n][k]
__global__ void k_transpose_w(const float* __restrict__ wq, const float* __restrict__ wk,
                              const float* __restrict__ wv, const float* __restrict__ wo,
                              ushort_t* __restrict__ wqkvt, ushort_t* __restrict__ wot) {
    __shared__ float t[64][65];
    int bx = blockIdx.x;
    int w = bx >> 8;            // 0..3 : WQ WK WV WO
    int ti = bx & 255;
    int k0 = (ti >> 4) * 64, n0 = (ti & 15) * 64;
    const float* src = (w == 0) ? wq : (w == 1) ? wk : (w == 2) ? wv : wo;
    ushort_t* dst = (w < 3) ? (wqkvt + (size_t)w * 1048576) : wot;
    for (int i = threadIdx.x; i < 4096; i += 256) {
        int r = i >> 6, c = i & 63;
        t[c][r] = src[(size_t)(k0 + r) * 1024 + n0 + c];
    }
    __syncthreads();
    for (int i = threadIdx.x; i < 4096; i += 256) {
        int r = i >> 6, c = i & 63;
        dst[(size_t)(n0 + r) * 1024 + k0 + c] = f2bf(t[r][c]);
    }
}

// ---------------------------------------------------------------- QKV GEMM, 256x192 tile, pipelined phases
// (proven round 6: 0 bank conflicts, counted vmcnt, 4 barriers/tile)
__global__ __launch_bounds__(512, 2) void k_gemm_qkv256(
    const ushort_t* __restrict__ A, const ushort_t* __restrict__ Bm,
    ushort_t* __restrict__ qd, ushort_t* __restrict__ kd, ushort_t* __restrict__ vd) {
    __shared__ __attribute__((aligned(16))) ushort_t lds[2 * 28672];   // 112 KiB

    const int tid = threadIdx.x, wid = tid >> 6, lane = tid & 63;
    const int lr = lane & 15, lg = lane >> 4;
    const int wm = wid >> 2, wn = wid & 3;

    int bid = blockIdx.x;                       // 512 = 64 per XCD
    int wg = (bid & 7) * 64 + (bid >> 3);       // bijective XCD swizzle
    const int by = wg >> 4, bx = wg & 15;
    const int row0 = by * 256, col0 = bx * 192;

    const int srcrow = lane >> 2;
    const int srccol = (((lane & 3) * 16) ^ ((lane >> 5) << 5)) >> 1;   // ushort units
    const ushort_t* aS = A  + (size_t)(row0 + srcrow) * 1024 + srccol;
    const ushort_t* bS = Bm + (size_t)(col0 + srcrow) * 1024 + srccol;
    const int rdoff = (lr * 64 + lg * 16) ^ ((lr >> 3) << 5);           // bytes

    const int s0 = (wid & 3) + ((wid >> 2) << 3);   // A sr set {0..3, 8..11}
    const int s1 = s0 + 4;                          // A sr set {4..7, 12..15}
    const int bmix_sr = 8 + (wid & 3);              // B sr 8..11
    const int bmix_sc = wid >> 2;

#define STG_A(kt, sr, sc) \
    __builtin_amdgcn_global_load_lds((const AS1 void*)(aS + (size_t)(sr) * 16384 + (kt) * 64 + (sc) * 32), \
        (AS3 void*)((AS3 char*)lds + ((kt) & 1) * 57344 + (sr) * 2048 + (sc) * 1024), 16, 0, 0)
#define STG_B(kt, sr, sc) \
    __builtin_amdgcn_global_load_lds((const AS1 void*)(bS + (size_t)(sr) * 16384 + (kt) * 64 + (sc) * 32), \
        (AS3 void*)((AS3 char*)lds + ((kt) & 1) * 57344 + 32768 + (sr) * 2048 + (sc) * 1024), 16, 0, 0)
#define GRP1(kt)  { STG_A(kt, s0, 0); STG_B(kt, wid, 0); }   // 2 loads
#define GRP2(kt)  { STG_A(kt, s1, 0); }                      // 1 load
#define GRP3(kt)  { STG_A(kt, s0, 1); STG_B(kt, wid, 1); }   // 2 loads
#define GTOP(kt)  { STG_A(kt, s1, 1); STG_B(kt, bmix_sr, bmix_sc); }  // 2 loads

    f32x4 acc[8][3] = {};

    // prologue: tile0 complete (7), tile1 in-loop groups (5)
    GRP1(0); GRP2(0); GRP3(0); GTOP(0);
    GRP1(1); GRP2(1); GRP3(1);

#pragma unroll 1
    for (int kt = 0; kt < 16; ++kt) {
        if (kt < 15) asm volatile("s_waitcnt vmcnt(5)" ::: "memory");
        else         asm volatile("s_waitcnt vmcnt(0)" ::: "memory");
        __builtin_amdgcn_s_barrier();                 // buffer kt valid for all waves
        if (kt < 15) GTOP(kt + 1);

        const char* bufA = (const char*)lds + (kt & 1) * 57344;
        const char* bufB = bufA + 32768;

        bf16x8 av0[4], av1[4], bv0[3], bv1[3];
        // reads for phase 0 (sc0, mh0) + B sc0
#pragma unroll
        for (int x = 0; x < 4; ++x)
            av0[x] = *reinterpret_cast<const bf16x8*>(bufA + (wm * 8 + x) * 2048 + rdoff);
#pragma unroll
        for (int x = 0; x < 3; ++x)
            bv0[x] = *reinterpret_cast<const bf16x8*>(bufB + (wn * 3 + x) * 2048 + rdoff);

        // ---- phase 0
#pragma unroll
        for (int x = 0; x < 4; ++x)
            av1[x] = *reinterpret_cast<const bf16x8*>(bufA + (wm * 8 + 4 + x) * 2048 + rdoff);
        __builtin_amdgcn_s_setprio(1);
#pragma unroll
        for (int mf = 0; mf < 4; ++mf)
#pragma unroll
            for (int nf = 0; nf < 3; ++nf)
                acc[mf][nf] = __builtin_amdgcn_mfma_f32_16x16x32_bf16(av0[mf], bv0[nf], acc[mf][nf], 0, 0, 0);
        __builtin_amdgcn_s_setprio(0);
        __builtin_amdgcn_s_barrier();

        // ---- phase 1
#pragma unroll
        for (int x = 0; x < 4; ++x)
            av0[x] = *reinterpret_cast<const bf16x8*>(bufA + (wm * 8 + x) * 2048 + 1024 + rdoff);
#pragma unroll
        for (int x = 0; x < 3; ++x)
            bv1[x] = *reinterpret_cast<const bf16x8*>(bufB + (wn * 3 + x) * 2048 + 1024 + rdoff);
        __builtin_amdgcn_s_setprio(1);
#pragma unroll
        for (int mf = 0; mf < 4; ++mf)
#pragma unroll
            for (int nf = 0; nf < 3; ++nf)
                acc[4 + mf][nf] = __builtin_amdgcn_mfma_f32_16x16x32_bf16(av1[mf], bv0[nf], acc[4 + mf][nf], 0, 0, 0);
        __builtin_amdgcn_s_setprio(0);
        if (kt < 14) GRP1(kt + 2);
        __builtin_amdgcn_s_barrier();

        // ---- phase 2
#pragma unroll
        for (int x = 0; x < 4; ++x)
            av1[x] = *reinterpret_cast<const bf16x8*>(bufA + (wm * 8 + 4 + x) * 2048 + 1024 + rdoff);
        __builtin_amdgcn_s_setprio(1);
#pragma unroll
        for (int mf = 0; mf < 4; ++mf)
#pragma unroll
            for (int nf = 0; nf < 3; ++nf)
                acc[mf][nf] = __builtin_amdgcn_mfma_f32_16x16x32_bf16(av0[mf], bv1[nf], acc[mf][nf], 0, 0, 0);
        __builtin_amdgcn_s_setprio(0);
        if (kt < 14) GRP2(kt + 2);
        __builtin_amdgcn_s_barrier();

        // ---- phase 3
        __builtin_amdgcn_s_setprio(1);
#pragma unroll
        for (int mf = 0; mf < 4; ++mf)
#pragma unroll
            for (int nf = 0; nf < 3; ++nf)
                acc[4 + mf][nf] = __builtin_amdgcn_mfma_f32_16x16x32_bf16(av1[mf], bv1[nf], acc[4 + mf][nf], 0, 0, 0);
        __builtin_amdgcn_s_setprio(0);
        if (kt < 14) GRP3(kt + 2);
    }
#undef STG_A
#undef STG_B
#undef GRP1
#undef GRP2
#undef GRP3
#undef GTOP

    // ---- epilogue: scatter to [B,H,T,Dh]; per-fragment Q/K/V select (tiles straddle)
#pragma unroll
    for (int mi = 0; mi < 8; ++mi) {
#pragma unroll
        for (int nf = 0; nf < 3; ++nf) {
            int col = col0 + wn * 48 + nf * 16 + lr;
            int w = col >> 10;
            int c1 = col & 1023;
            int h = c1 >> 6, dh = c1 & 63;
            ushort_t* dst = (w == 0) ? qd : (w == 1) ? kd : vd;
            const float osc = (w == 0) ? 0.18033688f : 1.0f;   // 0.125*log2(e) for Q
#pragma unroll
            for (int e = 0; e < 4; ++e) {
                int row = row0 + wm * 128 + mi * 16 + lg * 4 + e;
                int b = row >> 11, t = row & 2047;
                dst[(((size_t)(b * 16 + h)) * 2048 + t) * 64 + dh] = f2bf(acc[mi][nf][e] * osc);
            }
        }
    }
}

// ---------------------------------------------------------------- V transpose [bh][t][dh] -> [bh][dh][t]
__global__ __launch_bounds__(256) void k_transpose_v(const ushort_t* __restrict__ vd,
                                                     ushort_t* __restrict__ vt) {
    __shared__ __attribute__((aligned(16))) ushort_t tile[64 * 72];  // col ^= ((t>>3)&7)<<3
    int bid = blockIdx.x;            // 64 bh x 32 ttiles
    int bh = bid >> 5, tt = bid & 31;
    const ushort_t* src = vd + ((size_t)bh * 2048 + tt * 64) * 64;
    ushort_t* dst = vt + (size_t)bh * 2048 * 64 + tt * 64;
#pragma unroll
    for (int r = 0; r < 2; ++r) {
        int i = r * 256 + threadIdx.x;
        int t = i >> 3, c8 = (i & 7) * 8;
        us8 v = *reinterpret_cast<const us8*>(src + (size_t)t * 64 + c8);
        *reinterpret_cast<us8*>(&tile[t * 72 + (c8 ^ ((t >> 3) << 3))]) = v;
    }
    __syncthreads();
#pragma unroll
    for (int r = 0; r < 2; ++r) {
        int i = r * 256 + threadIdx.x;
        int dh = i >> 3, t8 = (i & 7) * 8;
        us8 o;
#pragma unroll
        for (int e = 0; e < 8; ++e)
            o[e] = tile[(t8 + e) * 72 + (dh ^ ((t8 >> 3) << 3))];
        *reinterpret_cast<us8*>(dst + (size_t)dh * 2048 + t8) = o;
    }
}

// ---------------------------------------------------------------- attention
// 512 blocks decoded bh = bid & 63 so all 8 pi-blocks of one bh land on one XCD
// (round-robin bid%8): K/V streamed from HBM once per XCD, shared via L2.
// Uniform work: pass 0 = q-tile 15-pi, pass 1 = q-tile pi -> 17 KV-128 tiles/block.
__global__ __launch_bounds__(256) void k_attn(
    const ushort_t* __restrict__ q, const ushort_t* __restrict__ k,
    const ushort_t* __restrict__ v, ushort_t* __restrict__ ctx) {
    __shared__ __attribute__((aligned(16))) ushort_t lsK[2 * 8192];  // 2 bufs x [2][64 key][64 dh]
    __shared__ __attribute__((aligned(16))) ushort_t lsV[2 * 8192];  // 2 bufs x [2][64 dh][64 key]

    const int tid = threadIdx.x, wid = tid >> 6, lane = tid & 63;
    const int l31 = lane & 31, hi = lane >> 5;
    const int bid = blockIdx.x;
    const int bh = bid & 63, pi = bid >> 6;      // bh in low bits -> XCD affinity
    const size_t base = (size_t)bh * 2048 * 64;
    const ushort_t* qg = q + base;
    const ushort_t* kg = k + base;
    const ushort_t* vtg = v + base;          // [dh][t]
    const int b = bh >> 4, h = bh & 15;

    const int skey = wid * 8 + (lane >> 3);
    const int scb0 = ((lane & 7) * 16) ^ ((skey & 7) << 4);  // swizzled byte-in-row
    const int kx = (l31 & 7) << 4;
    int koffA[4];
#pragma unroll
    for (int s = 0; s < 4; ++s)
        koffA[s] = l31 * 128 + ((s * 32 + hi * 16) ^ kx);

    us8 ow;
#pragma unroll
    for (int e = 0; e < 8; ++e) ow[e] = 0x3F80;              // bf16 1.0
    const bf16x8 onef = __builtin_bit_cast(bf16x8, ow);

#pragma unroll 1
    for (int pass = 0; pass < 2; ++pass) {
        const int qt = pass ? pi : (15 - pi);
        const int q0 = qt * 128;
        const int q0w = q0 + wid * 32;
        const int qrow = q0w + l31;
        const int njt = qt + 1;              // 128-key tiles

        bf16x8 qf[4];
#pragma unroll
        for (int s = 0; s < 4; ++s)
            qf[s] = *reinterpret_cast<const bf16x8*>(qg + (size_t)qrow * 64 + s * 16 + hi * 8);

        const ushort_t* kpr[4];
        const ushort_t* vpr[4];
#pragma unroll
        for (int r = 0; r < 4; ++r) {
            kpr[r] = kg + (size_t)(r * 32 + skey) * 64 + (scb0 >> 1);
            vpr[r] = vtg + (size_t)((r & 1) * 32 + skey) * 2048 + (r >> 1) * 64 + (scb0 >> 1);
        }

        f32x16 acc0 = {}, acc1 = {}, lacc = {};

        __syncthreads();                     // protect LDS from previous pass readers
#pragma unroll
        for (int r = 0; r < 4; ++r) {        // stage tile 0 -> buffer 0
            __builtin_amdgcn_global_load_lds((const AS1 void*)kpr[r],
                (AS3 void*)((AS3 char*)lsK + r * 4096 + wid * 1024), 16, 0, 0);
            __builtin_amdgcn_global_load_lds((const AS1 void*)vpr[r],
                (AS3 void*)((AS3 char*)lsV + r * 4096 + wid * 1024), 16, 0, 0);
        }

        unsigned bo = 0;
        for (int jt = 0; jt < njt; ++jt) {
            __syncthreads();                 // tile jt resident (each wave drained own vmcnt)
            const int j0 = jt << 7;
            if (jt + 1 < njt) {
                const unsigned nb = bo ^ 16384;
#pragma unroll
                for (int r = 0; r < 4; ++r) {
                    kpr[r] += 8192;
                    vpr[r] += 128;
                    __builtin_amdgcn_global_load_lds((const AS1 void*)kpr[r],
                        (AS3 void*)((AS3 char*)lsK + nb + r * 4096 + wid * 1024), 16, 0, 0);
                    __builtin_amdgcn_global_load_lds((const AS1 void*)vpr[r],
                        (AS3 void*)((AS3 char*)lsV + nb + r * 4096 + wid * 1024), 16, 0, 0);
                }
            }

#pragma unroll
            for (int hh = 0; hh < 2; ++hh) {
                const int j0h = j0 + hh * 64;
                if (j0h < q0w + 32) {
                    const char* bK = reinterpret_cast<const char*>(lsK) + bo + hh * 8192;
                    const char* bV = reinterpret_cast<const char*>(lsV) + bo + hh * 8192;

                    // ---- S^T = K x Q
                    f32x16 s0 = {}, s1 = {};
#pragma unroll
                    for (int s = 0; s < 4; ++s) {
                        bf16x8 ka = *reinterpret_cast<const bf16x8*>(bK + koffA[s]);
                        s0 = __builtin_amdgcn_mfma_f32_32x32x16_bf16(ka, qf[s], s0, 0, 0, 0);
                    }
#pragma unroll
                    for (int s = 0; s < 4; ++s) {
                        bf16x8 ka = *reinterpret_cast<const bf16x8*>(bK + 4096 + koffA[s]);
                        s1 = __builtin_amdgcn_mfma_f32_32x32x16_bf16(ka, qf[s], s1, 0, 0, 0);
                    }

                    // ---- P = exp2(S) with causal zeroing (no max tracking: scores bounded)
                    float p0[16], p1[16];
                    if (j0h + 63 > q0w) {
                        const int jh = j0h + 4 * hi;
#pragma unroll
                        for (int r = 0; r < 16; ++r) {
                            const int kl = jh + (r & 3) + 8 * (r >> 2);
                            float e0 = fast_exp2(s0[r]);
                            float e1 = fast_exp2(s1[r]);
                            p0[r] = (kl > qrow) ? 0.f : e0;
                            p1[r] = (kl + 32 > qrow) ? 0.f : e1;
                        }
                    } else {
#pragma unroll
                        for (int r = 0; r < 16; ++r) {
                            p0[r] = fast_exp2(s0[r]);
                            p1[r] = fast_exp2(s1[r]);
                        }
                    }

                    // ---- pack P -> bf16 frags; PV and row-sum via MFMA
#pragma unroll
                    for (int kb = 0; kb < 2; ++kb) {
                        const float* pp = kb ? p1 : p0;
                        unsigned pw[8];
#pragma unroll
                        for (int g = 0; g < 4; ++g) {
                            pw[2 * g]     = cvtpk_bf16(pp[4 * g],     pp[4 * g + 1]);
                            pw[2 * g + 1] = cvtpk_bf16(pp[4 * g + 2], pp[4 * g + 3]);
                        }
#pragma unroll
                        for (int j = 0; j < 2; ++j) {
                            asm("v_permlane32_swap_b32 %0, %1" : "+v"(pw[4 * j]),     "+v"(pw[4 * j + 2]));
                            asm("v_permlane32_swap_b32 %0, %1" : "+v"(pw[4 * j + 1]), "+v"(pw[4 * j + 3]));
                            u32x4 fw = { pw[4 * j], pw[4 * j + 1], pw[4 * j + 2], pw[4 * j + 3] };
                            bf16x8 pf = __builtin_bit_cast(bf16x8, fw);
                            const int jj = kb * 2 + j;
                            {
                                bf16x8 vf = *reinterpret_cast<const bf16x8*>(bV + koffA[jj]);
                                acc0 = __builtin_amdgcn_mfma_f32_32x32x16_bf16(vf, pf, acc0, 0, 0, 0);
                            }
                            {
                                bf16x8 vf = *reinterpret_cast<const bf16x8*>(bV + 4096 + koffA[jj]);
                                acc1 = __builtin_amdgcn_mfma_f32_32x32x16_bf16(vf, pf, acc1, 0, 0, 0);
                            }
                            lacc = __builtin_amdgcn_mfma_f32_32x32x16_bf16(onef, pf, lacc, 0, 0, 0);
                        }
                    }
                }
            }
            bo ^= 16384;
        }

        // ---- epilogue: ctx[b][t=qrow][h*64 + dh]
        float inv = 1.0f / lacc[0];
        size_t orow = ((size_t)(b * 2048 + qrow)) * 1024 + h * 64;
#pragma unroll
        for (int g = 0; g < 4; ++g) {
            us4 o0 = { f2bf(acc0[4 * g] * inv),     f2bf(acc0[4 * g + 1] * inv),
                       f2bf(acc0[4 * g + 2] * inv), f2bf(acc0[4 * g + 3] * inv) };
            *reinterpret_cast<us4*>(&ctx[orow + 8 * g + 4 * hi]) = o0;
            us4 o1 = { f2bf(acc1[4 * g] * inv),     f2bf(acc1[4 * g + 1] * inv),
                       f2bf(acc1[4 * g + 2] * inv), f2bf(acc1[4 * g + 3] * inv) };
            *reinterpret_cast<us4*>(&ctx[orow + 32 + 8 * g + 4 * hi]) = o1;
        }
    }
}

// ---------------------------------------------------------------- out GEMM (+bias, f32 out)
// 128x128 tile, BK=64, 4 waves (2x2), 4-phase pipelined schedule (round-6 skeleton),
// dbuf 64 KiB, counted vmcnt, 0-conflict swizzled LDS, XCD swizzle on 512 blocks.
__global__ __launch_bounds__(256, 2) void k_gemm_out(
    const ushort_t* __restrict__ cb, const ushort_t* __restrict__ wot,
    const float* __restrict__ bO, float* __restrict__ out) {
    __shared__ __attribute__((aligned(16))) ushort_t lds[2 * 16384];   // 64 KiB

    const int tid = threadIdx.x, wid = tid >> 6, lane = tid & 63;
    const int lr = lane & 15, lg = lane >> 4;
    const int wm = wid >> 1, wn = wid & 1;

    int bid = blockIdx.x;                       // 512 = 64 per XCD
    int wg = (bid & 7) * 64 + (bid >> 3);       // bijective XCD swizzle
    const int by = wg >> 3, bx = wg & 7;
    const int row0 = by * 128, col0 = bx * 128;

    const int srcrow = lane >> 2;
    const int srccol = (((lane & 3) * 16) ^ ((lane >> 5) << 5)) >> 1;   // ushort units
    const ushort_t* aS = cb  + (size_t)(row0 + srcrow) * 1024 + srccol;
    const ushort_t* bS = wot + (size_t)(col0 + srcrow) * 1024 + srccol;
    const int rdoff = (lr * 64 + lg * 16) ^ ((lr >> 3) << 5);           // bytes

#define STG_A(kt, sr, sc) \
    __builtin_amdgcn_global_load_lds((const AS1 void*)(aS + (size_t)(sr) * 16384 + (kt) * 64 + (sc) * 32), \
        (AS3 void*)((AS3 char*)lds + ((kt) & 1) * 32768 + (sr) * 2048 + (sc) * 1024), 16, 0, 0)
#define STG_B(kt, sr, sc) \
    __builtin_amdgcn_global_load_lds((const AS1 void*)(bS + (size_t)(sr) * 16384 + (kt) * 64 + (sc) * 32), \
        (AS3 void*)((AS3 char*)lds + ((kt) & 1) * 32768 + 16384 + (sr) * 2048 + (sc) * 1024), 16, 0, 0)
#define GRP1(kt)  { STG_A(kt, wid, 0); STG_A(kt, wid + 4, 0); STG_B(kt, wid, 0); STG_B(kt, wid + 4, 0); }
#define GTOP(kt)  { STG_A(kt, wid, 1); STG_A(kt, wid + 4, 1); STG_B(kt, wid, 1); STG_B(kt, wid + 4, 1); }

    f32x4 acc[4][4] = {};

    GRP1(0); GTOP(0); GRP1(1);

#pragma unroll 1
    for (int kt = 0; kt < 16; ++kt) {
        if (kt < 15) asm volatile("s_waitcnt vmcnt(4)" ::: "memory");
        else         asm volatile("s_waitcnt vmcnt(0)" ::: "memory");
        __builtin_amdgcn_s_barrier();
        if (kt < 15) GTOP(kt + 1);

        const char* bufA = (const char*)lds + (kt & 1) * 32768;
        const char* bufB = bufA + 16384;

        bf16x8 av0[2], av1[2], bv0[4], bv1[4];
        // reads for phase 0 (sc0, mf 0-1) + B sc0
#pragma unroll
        for (int x = 0; x < 2; ++x)
            av0[x] = *reinterpret_cast<const bf16x8*>(bufA + (wm * 4 + x) * 2048 + rdoff);
#pragma unroll
        for (int x = 0; x < 4; ++x)
            bv0[x] = *reinterpret_cast<const bf16x8*>(bufB + (wn * 4 + x) * 2048 + rdoff);

        // ---- phase 0: mf01 kk0; reads mf23 sc0
#pragma unroll
        for (int x = 0; x < 2; ++x)
            av1[x] = *reinterpret_cast<const bf16x8*>(bufA + (wm * 4 + 2 + x) * 2048 + rdoff);
        __builtin_amdgcn_s_setprio(1);
#pragma unroll
        for (int mf = 0; mf < 2; ++mf)
#pragma unroll
            for (int nf = 0; nf < 4; ++nf)
                acc[mf][nf] = __builtin_amdgcn_mfma_f32_16x16x32_bf16(av0[mf], bv0[nf], acc[mf][nf], 0, 0, 0);
        __builtin_amdgcn_s_setprio(0);
        __builtin_amdgcn_s_barrier();

        // ---- phase 1: mf23 kk0; reads mf01 sc1 + B sc1; stage GRP1(kt+2)
#pragma unroll
        for (int x = 0; x < 2; ++x)
            av0[x] = *reinterpret_cast<const bf16x8*>(bufA + (wm * 4 + x) * 2048 + 1024 + rdoff);
#pragma unroll
        for (int x = 0; x < 4; ++x)
            bv1[x] = *reinterpret_cast<const bf16x8*>(bufB + (wn * 4 + x) * 2048 + 1024 + rdoff);
        __builtin_amdgcn_s_setprio(1);
#pragma unroll
        for (int mf = 0; mf < 2; ++mf)
#pragma unroll
            for (int nf = 0; nf < 4; ++nf)
                acc[2 + mf][nf] = __builtin_amdgcn_mfma_f32_16x16x32_bf16(av1[mf], bv0[nf], acc[2 + mf][nf], 0, 0, 0);
        __builtin_amdgcn_s_setprio(0);
        if (kt < 14) GRP1(kt + 2);
        __builtin_amdgcn_s_barrier();

        // ---- phase 2: mf01 kk1; reads mf23 sc1
#pragma unroll
        for (int x = 0; x < 2; ++x)
            av1[x] = *reinterpret_cast<const bf16x8*>(bufA + (wm * 4 + 2 + x) * 2048 + 1024 + rdoff);
        __builtin_amdgcn_s_setprio(1);
#pragma unroll
        for (int mf = 0; mf < 2; ++mf)
#pragma unroll
            for (int nf = 0; nf < 4; ++nf)
                acc[mf][nf] = __builtin_amdgcn_mfma_f32_16x16x32_bf16(av0[mf], bv1[nf], acc[mf][nf], 0, 0, 0);
        __builtin_amdgcn_s_setprio(0);
        __builtin_amdgcn_s_barrier();

        // ---- phase 3: mf23 kk1
        __builtin_amdgcn_s_setprio(1);
#pragma unroll
        for (int mf = 0; mf < 2; ++mf)
#pragma unroll
            for (int nf = 0; nf < 4; ++nf)
                acc[2 + mf][nf] = __builtin_amdgcn_mfma_f32_16x16x32_bf16(av1[mf], bv1[nf], acc[2 + mf][nf], 0, 0, 0);
        __builtin_amdgcn_s_setprio(0);
    }
#undef STG_A
#undef STG_B
#undef GRP1
#undef GTOP

#pragma unroll
    for (int mf = 0; mf < 4; ++mf) {
#pragma unroll
        for (int nf = 0; nf < 4; ++nf) {
            int col = col0 + wn * 64 + nf * 16 + lr;
            float bias = bO[col];
#pragma unroll
            for (int e = 0; e < 4; ++e) {
                int row = row0 + wm * 64 + mf * 16 + lg * 4 + e;
                out[(size_t)row * 1024 + col] = acc[mf][nf][e] + bias;
            }
        }
    }
}

// ---------------------------------------------------------------- launch
extern "C" void kernel_launch(void* const* d_in, const int* in_sizes, int n_in,
                              void* d_out, int out_size, void* d_ws, size_t ws_size,
                              hipStream_t stream) {
    const float* x  = (const float*)d_in[0];
    const float* wq = (const float*)d_in[1];
    const float* wk = (const float*)d_in[2];
    const float* wv = (const float*)d_in[3];
    const float* wo = (const float*)d_in[4];
    const float* bo = (const float*)d_in[5];
    float* out = (float*)d_out;

    char* ws = (char*)d_ws;
    ushort_t* xb    = (ushort_t*)(ws);                 // 16 MB   x bf16 [8192][1024]; reused as V^T after gemm
    ushort_t* wqkvt = (ushort_t*)(ws + 16777216);      // 6 MB    [3][1024 n][1024 k] = [3072][1024]
    ushort_t* wot   = (ushort_t*)(ws + 23068672);      // 2 MB    [1024 n][1024 k]
    ushort_t* qd    = (ushort_t*)(ws + 25165824);      // 16 MB   [B,H,T,Dh] (pre-scaled)
    ushort_t* kd    = (ushort_t*)(ws + 41943040);      // 16 MB   [B,H,T,Dh]
    ushort_t* vd    = (ushort_t*)(ws + 58720256);      // 16 MB   [B,H,T,Dh]
    ushort_t* cd    = (ushort_t*)(ws + 75497472);      // 16 MB   ctx bf16 [8192][1024]
    ushort_t* vt    = xb;                              // V^T [B,H,Dh,T] (xb dead after gemm_qkv)

    k_convert_x<<<2048, 256, 0, stream>>>(x, xb, 8192 * 1024 / 4);
    k_transpose_w<<<1024, 256, 0, stream>>>(wq, wk, wv, wo, wqkvt, wot);
    k_gemm_qkv256<<<512, 512, 0, stream>>>(xb, wqkvt, qd, kd, vd);
    k_transpose_v<<<2048, 256, 0, stream>>>(vd, vt);
    k_attn<<<512, 256, 0, stream>>>(qd, kd, vt, cd);
    k_gemm_out<<<dim3(512), 256, 0, stream>>>(cd, wot, bo, out);
}